// Round 9
// baseline (3936.211 us; speedup 1.0000x reference)
//
#include <hip/hip_runtime.h>
#include <hip/hip_bf16.h>

#define Vv 32000
#define Ee 256
#define Hh 256
#define Bb 32
#define TEe 128
#define TDd 64

typedef __attribute__((ext_vector_type(4))) float f32x4;
typedef __attribute__((ext_vector_type(8))) short short8;
typedef __attribute__((ext_vector_type(2))) unsigned int uint2v;
typedef __attribute__((ext_vector_type(4))) unsigned int uint4v;

static __device__ __forceinline__ unsigned short f2bf(float f){
  unsigned u = __float_as_uint(f);
  u += 0x7fffu + ((u >> 16) & 1u);           // round-to-nearest-even
  return (unsigned short)(u >> 16);
}
static __device__ __forceinline__ unsigned pack2(float a, float b){
  return ((unsigned)f2bf(b) << 16) | (unsigned)f2bf(a);
}
// dot of 8 packed bf16 (uint4) with 8 f32
static __device__ __forceinline__ float dot8(uint4v u, const float* hh){
  float s = 0.f;
  #pragma unroll
  for (int i = 0; i < 4; ++i){
    unsigned w = u[i];
    s = fmaf(__uint_as_float(w << 16),        hh[2*i],   s);
    s = fmaf(__uint_as_float(w & 0xffff0000u), hh[2*i+1], s);
  }
  return s;
}
static __device__ __forceinline__ float sigmoidf_(float x){
  return 1.f / (1.f + __expf(-x));
}

// ---------------- small prep kernels ----------------
__global__ void k_sizes(const int* __restrict__ enc_in, int* __restrict__ sizes){
  int b = threadIdx.x;
  if (b < Bb){
    int c = 0;
    for (int t = 0; t < TEe; ++t) c += (enc_in[b*TEe + t] > 0);
    sizes[b] = c;
  }
}

__global__ void k_gather(const int* __restrict__ tok, const float* __restrict__ embW,
                         float* __restrict__ out, int rows){
  int i = blockIdx.x * 256 + threadIdx.x;
  int r = i >> 8, c = i & 255;
  if (r < rows) out[i] = embW[(size_t)tok[r]*Ee + c];
}

__global__ void k_extract_bf16(const float* __restrict__ src, unsigned short* __restrict__ dst,
                               int n){
  int i = blockIdx.x * 256 + threadIdx.x;
  if (i < n) dst[i] = f2bf(src[i]);
}

// f32 [rows][256] -> chunked bf16 [32][rows][8]
__global__ void k_chunkw(const float* __restrict__ src, unsigned short* __restrict__ dst, int rows){
  int idx = blockIdx.x * 256 + threadIdx.x;
  if (idx < rows * 256){
    int i = idx & 7, r = (idx >> 3) % rows, kb = idx / (rows * 8);
    dst[idx] = f2bf(src[(size_t)r*256 + kb*8 + i]);
  }
}

// projf f32 [B*TE][768] -> chunked bf16 [B][16][768][8]
__global__ void k_projchunk(const float* __restrict__ in, unsigned short* __restrict__ out){
  int idx = blockIdx.x * 256 + threadIdx.x;
  int i = idx & 7;
  int t1 = idx >> 3;
  int n = t1 % 768;
  int t2 = t1 / 768;
  int kb = t2 & 15, b = t2 >> 4;
  out[idx] = f2bf(in[(size_t)(b*TEe + kb*8 + i)*768 + n]);
}

// ---------------- bf16 MFMA GEMM: C[M,N] = A[M,K] * B^T + bias ----------------
template<bool A_BF16, bool B_BF16, bool B_KMAJOR, bool OUT_BF16>
__global__ __launch_bounds__(256) void k_gemm(
  const void* __restrict__ Av, const void* __restrict__ Bv,
  const float* __restrict__ bias, void* __restrict__ Cv,
  int M, int N, int K, int lda, int ldb, int ldc)
{
  __shared__ unsigned short lA[128*40];
  __shared__ unsigned short lB[128*40];
  const int tid  = threadIdx.x;
  const int lane = tid & 63;
  const int w = tid >> 6, wr = w >> 1, wc = w & 1;
  const int m0 = blockIdx.y * 128, n0 = blockIdx.x * 128;
  f32x4 acc[4][4];
  #pragma unroll
  for (int i = 0; i < 4; ++i)
    #pragma unroll
    for (int j = 0; j < 4; ++j) acc[i][j] = (f32x4){0.f,0.f,0.f,0.f};

  for (int k0 = 0; k0 < K; k0 += 32){
    if (A_BF16){
      const unsigned short* A = (const unsigned short*)Av;
      #pragma unroll
      for (int it = 0; it < 2; ++it){
        int idx = tid + it*256; int r = idx >> 2, q = idx & 3;
        *(uint4v*)&lA[r*40 + q*8] = *(const uint4v*)(A + (size_t)(m0+r)*lda + k0 + q*8);
      }
    } else {
      const float* A = (const float*)Av;
      #pragma unroll
      for (int it = 0; it < 4; ++it){
        int idx = tid + it*256; int r = idx >> 3, q = idx & 7;
        f32x4 v = *(const f32x4*)(A + (size_t)(m0+r)*lda + k0 + q*4);
        uint2v pk; pk[0] = pack2(v[0], v[1]); pk[1] = pack2(v[2], v[3]);
        *(uint2v*)&lA[r*40 + q*4] = pk;
      }
    }
    if (B_KMAJOR){
      const float* Bp = (const float*)Bv;
      #pragma unroll
      for (int it = 0; it < 4; ++it){
        int idx = tid + it*256; int kk = idx >> 5, nq = idx & 31;
        f32x4 v = *(const f32x4*)(Bp + (size_t)(k0+kk)*ldb + n0 + nq*4);
        #pragma unroll
        for (int s2 = 0; s2 < 4; ++s2) lB[(nq*4+s2)*40 + kk] = f2bf(v[s2]);
      }
    } else if (B_BF16){
      const unsigned short* Bp = (const unsigned short*)Bv;
      #pragma unroll
      for (int it = 0; it < 2; ++it){
        int idx = tid + it*256; int r = idx >> 2, q = idx & 3;
        *(uint4v*)&lB[r*40 + q*8] = *(const uint4v*)(Bp + (size_t)(n0+r)*ldb + k0 + q*8);
      }
    } else {
      const float* Bp = (const float*)Bv;
      #pragma unroll
      for (int it = 0; it < 4; ++it){
        int idx = tid + it*256; int r = idx >> 3, q = idx & 7;
        f32x4 v = *(const f32x4*)(Bp + (size_t)(n0+r)*ldb + k0 + q*4);
        uint2v pk; pk[0] = pack2(v[0], v[1]); pk[1] = pack2(v[2], v[3]);
        *(uint2v*)&lB[r*40 + q*4] = pk;
      }
    }
    __syncthreads();
    short8 av[4], bv[4];
    #pragma unroll
    for (int i = 0; i < 4; ++i)
      av[i] = *(const short8*)&lA[(wr*64 + i*16 + (lane&15))*40 + (lane>>4)*8];
    #pragma unroll
    for (int j = 0; j < 4; ++j)
      bv[j] = *(const short8*)&lB[(wc*64 + j*16 + (lane&15))*40 + (lane>>4)*8];
    #pragma unroll
    for (int i = 0; i < 4; ++i)
      #pragma unroll
      for (int j = 0; j < 4; ++j)
        acc[i][j] = __builtin_amdgcn_mfma_f32_16x16x32_bf16(av[i], bv[j], acc[i][j], 0, 0, 0);
    __syncthreads();
  }
  #pragma unroll
  for (int i = 0; i < 4; ++i){
    #pragma unroll
    for (int j = 0; j < 4; ++j){
      int col = n0 + wc*64 + j*16 + (lane & 15);
      float bb = bias ? bias[col] : 0.f;
      #pragma unroll
      for (int r = 0; r < 4; ++r){
        int row = m0 + wr*64 + i*16 + (lane>>4)*4 + r;
        float v = acc[i][j][r] + bb;
        if (OUT_BF16) ((unsigned short*)Cv)[(size_t)row*ldc + col] = f2bf(v);
        else          ((float*)Cv)[(size_t)row*ldc + col] = v;
      }
    }
  }
}

// ================= 3-block cooperative recurrences =================
// Block k of a unit owns gate-triples j in [85k, 85k+c), c = 85/85/86,
// holding Wh rows {j, j+256, j+512} fully in LDS (132KB) -> zero
// steady-state weight streaming. Per step: 256-float h-slice exchange via
// global memory, step-stamped release/acquire flags, double-buffered slots.
// DEADLOCK FIX (R8 hung): flag STORE in wave 0 (T==0); partner SPINS in
// waves 1,2 (T==64,T==128) — never mix store+spin in one wave (divergent
// execution order is compiler-chosen; spin-first deadlocks globally).
// Spins are bounded (degrade to wrong-result, never a 600s hang).

// ---------------- encoder: 192 blocks = 3 x (dir,b), 768 threads ----------------
__global__ __launch_bounds__(768) void k_encoder(
  const unsigned short* __restrict__ Whf, const unsigned short* __restrict__ Whb,
  const float* __restrict__ bhf, const float* __restrict__ bhb,
  const float* __restrict__ gif, const float* __restrict__ gib,
  float* __restrict__ encoded,
  float* __restrict__ hbuf, int* __restrict__ flags)
{
  extern __shared__ char smem[];
  unsigned short* lw = (unsigned short*)smem;        // 258*512 = 132096
  float* h   = (float*)(smem + 132096);              // 1024
  float* par = (float*)(smem + 133120);              // 2*264*4 = 2112 -> 135232
  const int g = blockIdx.x;
  const int u = g & 63, k = g >> 6;
  const int dir = u & 1, b = u >> 1;
  const int o = 85*k, c = (k == 2) ? 86 : 85;
  const unsigned short* Wh = dir ? Whb : Whf;
  const float* bh = dir ? bhb : bhf;
  const float* gi = dir ? gib : gif;
  const int T = threadIdx.x;
  for (int sec = 0; sec < 3; ++sec)
    for (int cc = T; cc < c*32; cc += 768){
      int rl = cc >> 5, q = cc & 31;
      int R = sec*86 + rl;
      *(uint4v*)&lw[(R*32 + (q ^ (R & 31)))*8] =
          *(const uint4v*)(Wh + (size_t)q*6144 + (size_t)(sec*256 + o + rl)*8);
    }
  for (int idx = T; idx < 256; idx += 768) h[idx] = 0.f;
  float bh0 = 0.f, bh1 = 0.f, bh2 = 0.f;
  if (T < c){ bh0 = bh[o+T]; bh1 = bh[o+T+256]; bh2 = bh[o+T+512]; }
  const int R = T >> 1, half = T & 1;
  const int sec = R / 86, rl = R % 86;
  const bool dact = (R < 258) && (rl < c);
  __syncthreads();
  for (int s = 0; s < TEe; ++s){
    const int t = dir ? (TEe-1-s) : s;
    float g0 = 0.f, g1 = 0.f, g2 = 0.f;
    if (T < c){
      const float* grow = gi + (size_t)(b*TEe + t)*768;
      g0 = grow[o+T]; g1 = grow[o+T+256]; g2 = grow[o+T+512];
    }
    if (dact){
      float a = 0.f;
      const unsigned short* lwr = lw + R*256;
      #pragma unroll
      for (int i = 0; i < 16; ++i){
        const int q = half*16 + i;
        float hr[8];
        *(f32x4*)&hr[0] = *(const f32x4*)&h[q*8];
        *(f32x4*)&hr[4] = *(const f32x4*)&h[q*8+4];
        a += dot8(*(const uint4v*)(lwr + ((q ^ (R & 31)) << 3)), hr);
      }
      par[half*264 + R] = a;
    }
    __syncthreads();                   // B1: partials ready
    const int stamp = s + 1, sl = stamp & 1;
    if (T < c){
      const int j = o + T;
      const float a0 = par[T]      + par[264+T]      + bh0;
      const float a1 = par[86+T]   + par[264+86+T]   + bh1;
      const float a2 = par[172+T]  + par[264+172+T]  + bh2;
      const float r = sigmoidf_(g0 + a0);
      const float z = sigmoidf_(g1 + a1);
      const float n = tanhf(g2 + r*a2);
      const float hnew = (1.f - z)*n + z*h[j];
      h[j] = hnew;
      encoded[(size_t)(b*TEe + t)*512 + dir*256 + j] = hnew;
      if (s + 1 < TEe){
        hbuf[(u*2 + sl)*256 + j] = hnew;
        __threadfence();               // drain slice stores (device scope)
      }
    }
    if (s + 1 == TEe) break;           // last step: no exchange needed
    __syncthreads();                   // B2: slice stores + fences done
    if (T == 0){                       // wave 0: release our stamp
      __hip_atomic_store(&flags[((u*2 + sl)*3 + k)*16], stamp,
                         __ATOMIC_RELEASE, __HIP_MEMORY_SCOPE_AGENT);
    }
    if (T == 64 || T == 128){          // waves 1,2: wait for partners (bounded)
      const int pk = (k + (T >> 6)) % 3;
      int spins = 0;
      while (__hip_atomic_load(&flags[((u*2 + sl)*3 + pk)*16],
                               __ATOMIC_ACQUIRE, __HIP_MEMORY_SCOPE_AGENT) < stamp){
        if (++spins > 65536) break;
        __builtin_amdgcn_s_sleep(2);
      }
      __threadfence();
    }
    __syncthreads();                   // B3: partner slices visible
    {
      const float* hb = hbuf + (u*2 + sl)*256;
      for (int idx = T; idx < 256; idx += 768)
        if (idx < o || idx >= o + c) h[idx] = hb[idx];
    }
    __syncthreads();                   // B4: h complete for next step
  }
}

// encb2[r] = encoded[r,:512] . W2_b
__global__ void k_encb2(const float* __restrict__ encoded, const float* __restrict__ W2b,
                        float* __restrict__ encb2){
  int r = blockIdx.x, l = threadIdx.x;
  const float* e = encoded + (size_t)r*512;
  float s = 0.f;
  for (int k = l; k < 512; k += 64) s += e[k]*W2b[k];
  for (int off = 32; off; off >>= 1) s += __shfl_down(s, off);
  if (l == 0) encb2[r] = s;
}

__global__ void k_hinit(const float* __restrict__ encoded, const int* __restrict__ sizes,
                        const float* __restrict__ W1w, const float* __restrict__ W1b,
                        float* __restrict__ h0){
  int b = blockIdx.x, o = threadIdx.x;
  int idx = sizes[b] - 1;
  idx = idx < 0 ? 0 : (idx > TEe-1 ? TEe-1 : idx);
  const float* ls = encoded + (size_t)(b*TEe + idx)*512;
  const float* wv = W1w + (size_t)o*512;
  float s = W1b[o];
  for (int k = 0; k < 512; k += 4){
    f32x4 a = *(const f32x4*)(ls + k);
    f32x4 w4 = *(const f32x4*)(wv + k);
    s = fmaf(a[0],w4[0], fmaf(a[1],w4[1], fmaf(a[2],w4[2], fmaf(a[3],w4[3], s))));
  }
  h0[b*256 + o] = s;
}

// ---------------- decoder: 96 blocks = 3 x batch, 768 threads ----------------
// Whd owned rows in LDS; scores+softmax replicated per block; ctx projection
// for owned rows. ONE h-slice exchange per step (same protocol as encoder).
// n-gate: ctx projection stays OUTSIDE the r* product (ref semantics).
__global__ __launch_bounds__(768) void k_decoder(
  const unsigned short* __restrict__ Whd, const float* __restrict__ bhd,
  const float* __restrict__ gidx,            // [B][TD][768] f32 (includes bi_d)
  const unsigned short* __restrict__ encw2,  // [B*TE][256] bf16
  const float* __restrict__ encb2,           // [B*TE]
  const unsigned short* __restrict__ projt,  // [B][16][768][8] bf16
  const float* __restrict__ h0,
  unsigned short* __restrict__ outs_bf,      // [B][TD][256] bf16
  float* __restrict__ hbuf, int* __restrict__ flags)
{
  extern __shared__ char smem[];
  unsigned short* lw = (unsigned short*)smem;        // 132096
  float* h   = (float*)(smem + 132096);              // 1024
  float* par = (float*)(smem + 133120);              // 2112
  float* gcs = (float*)(smem + 135232);              // 1056
  float* p   = (float*)(smem + 136288);              // 512
  float* ebl = (float*)(smem + 136800);              // 512  -> total 137312
  const int g = blockIdx.x;
  const int u = g & 31, k = g >> 5;
  const int b = u;
  const int o = 85*k, c = (k == 2) ? 86 : 85;
  const int T = threadIdx.x;
  for (int sec = 0; sec < 3; ++sec)
    for (int cc = T; cc < c*32; cc += 768){
      int rl = cc >> 5, q = cc & 31;
      int R = sec*86 + rl;
      *(uint4v*)&lw[(R*32 + (q ^ (R & 31)))*8] =
          *(const uint4v*)(Whd + (size_t)q*6144 + (size_t)(sec*256 + o + rl)*8);
    }
  for (int idx = T; idx < 256; idx += 768) h[idx] = h0[b*256 + idx];
  for (int idx = T; idx < 258; idx += 768) gcs[idx] = 0.f;
  if (T < TEe) ebl[T] = encb2[b*TEe + T];
  float bh0 = 0.f, bh1 = 0.f, bh2 = 0.f;
  if (T < c){ bh0 = bhd[o+T]; bh1 = bhd[o+T+256]; bh2 = bhd[o+T+512]; }
  const int R = T >> 1, half = T & 1;
  const int sec = R / 86, rl = R % 86;
  const bool dact = (R < 258) && (rl < c);
  uint4v ew[8];
  if (T < 512){
    const int pos = T >> 2, q = T & 3;
    const unsigned short* er = encw2 + (((size_t)(b*TEe + pos)) << 8) + q*64;
    #pragma unroll
    for (int i = 0; i < 8; ++i) ew[i] = *(const uint4v*)(er + i*8);
  }
  uint4v pj[8];
  if (dact){
    const unsigned short* ptc = projt + (size_t)b*98304;
    const int gr = sec*256 + o + rl;
    #pragma unroll
    for (int i = 0; i < 8; ++i)
      pj[i] = *(const uint4v*)(ptc + (size_t)(half*8 + i)*6144 + gr*8);
  }
  __syncthreads();
  for (int t = 0; t < TDd; ++t){
    float g0 = 0.f, g1 = 0.f, g2 = 0.f;
    if (T < c){
      const float* grow = gidx + (size_t)(b*TDd + t)*768;
      g0 = grow[o+T]; g1 = grow[o+T+256]; g2 = grow[o+T+512];
    }
    if (dact){
      float a = 0.f;
      const unsigned short* lwr = lw + R*256;
      #pragma unroll
      for (int i = 0; i < 16; ++i){
        const int q = half*16 + i;
        float hr[8];
        *(f32x4*)&hr[0] = *(const f32x4*)&h[q*8];
        *(f32x4*)&hr[4] = *(const f32x4*)&h[q*8+4];
        a += dot8(*(const uint4v*)(lwr + ((q ^ (R & 31)) << 3)), hr);
      }
      par[half*264 + R] = a;
    }
    __syncthreads();                   // B1
    const int stamp = t + 1, sl = stamp & 1;
    if (T < c){
      const int j = o + T;
      const float a0 = par[T]     + par[264+T]     + bh0;
      const float a1 = par[86+T]  + par[264+86+T]  + bh1;
      const float a2 = par[172+T] + par[264+172+T] + bh2;
      const float r = sigmoidf_(g0 + gcs[T] + a0);
      const float z = sigmoidf_(g1 + gcs[86+T] + a1);
      const float n = tanhf(g2 + gcs[172+T] + r*a2);
      const float hnew = (1.f - z)*n + z*h[j];
      h[j] = hnew;
      outs_bf[(size_t)(b*TDd + t)*256 + j] = f2bf(hnew);
      if (t + 1 < TDd){
        hbuf[(u*2 + sl)*256 + j] = hnew;
        __threadfence();
      }
    }
    if (t + 1 == TDd) break;           // last step: outs written, done
    __syncthreads();                   // B2
    if (T == 0){                       // wave 0: release our stamp
      __hip_atomic_store(&flags[((u*2 + sl)*3 + k)*16], stamp,
                         __ATOMIC_RELEASE, __HIP_MEMORY_SCOPE_AGENT);
    }
    if (T == 64 || T == 128){          // waves 1,2: wait for partners (bounded)
      const int pk = (k + (T >> 6)) % 3;
      int spins = 0;
      while (__hip_atomic_load(&flags[((u*2 + sl)*3 + pk)*16],
                               __ATOMIC_ACQUIRE, __HIP_MEMORY_SCOPE_AGENT) < stamp){
        if (++spins > 65536) break;
        __builtin_amdgcn_s_sleep(2);
      }
      __threadfence();
    }
    __syncthreads();                   // B3
    {
      const float* hb = hbuf + (u*2 + sl)*256;
      for (int idx = T; idx < 256; idx += 768)
        if (idx < o || idx >= o + c) h[idx] = hb[idx];
    }
    __syncthreads();                   // B4: h_t complete
    // scores (replicated): 4 threads per enc position
    if (T < 512){
      const int pos = T >> 2, q = T & 3;
      float s = 0.f;
      #pragma unroll
      for (int i = 0; i < 8; ++i){
        float hr[8];
        *(f32x4*)&hr[0] = *(const f32x4*)&h[q*64 + i*8];
        *(f32x4*)&hr[4] = *(const f32x4*)&h[q*64 + i*8 + 4];
        s += dot8(ew[i], hr);
      }
      s += __shfl_xor(s, 1);
      s += __shfl_xor(s, 2);
      if (q == 0) p[pos] = s + ebl[pos];
    }
    __syncthreads();                   // B5
    if (T < 64){
      float m = fmaxf(p[T], p[T+64]);
      for (int off = 32; off; off >>= 1) m = fmaxf(m, __shfl_xor(m, off));
      float e0 = __expf(p[T] - m), e1 = __expf(p[T+64] - m);
      float ss = e0 + e1;
      for (int off = 32; off; off >>= 1) ss += __shfl_xor(ss, off);
      float inv = 1.f / ss;
      p[T] = e0*inv; p[T+64] = e1*inv;
    }
    __syncthreads();                   // B6: softmax done
    if (dact){
      float s = 0.f;
      #pragma unroll
      for (int i = 0; i < 8; ++i){
        float pr[8];
        *(f32x4*)&pr[0] = *(const f32x4*)&p[(half*8 + i)*8];
        *(f32x4*)&pr[4] = *(const f32x4*)&p[(half*8 + i)*8 + 4];
        s += dot8(pj[i], pr);
      }
      s += __shfl_xor(s, 1);
      if (half == 0) gcs[R] = s;
    }
    // no barrier: gates read gcs only after next step's B1
  }
}

extern "C" void kernel_launch(void* const* d_in, const int* in_sizes, int n_in,
                              void* d_out, int out_size, void* d_ws, size_t ws_size,
                              hipStream_t stream)
{
  (void)in_sizes; (void)n_in; (void)out_size;
  const int*   enc_in = (const int*)d_in[0];
  const int*   dec_in = (const int*)d_in[1];
  const float* embW   = (const float*)d_in[2];
  const float* Wi_f   = (const float*)d_in[3];
  const float* Wh_f   = (const float*)d_in[4];
  const float* bi_f   = (const float*)d_in[5];
  const float* bh_f   = (const float*)d_in[6];
  const float* Wi_b   = (const float*)d_in[7];
  const float* Wh_b   = (const float*)d_in[8];
  const float* bi_b   = (const float*)d_in[9];
  const float* bh_b   = (const float*)d_in[10];
  const float* Wi_d   = (const float*)d_in[11];
  const float* Wh_d   = (const float*)d_in[12];
  const float* bi_d   = (const float*)d_in[13];
  const float* bh_d   = (const float*)d_in[14];
  const float* W1_w   = (const float*)d_in[15];
  const float* W1_b   = (const float*)d_in[16];
  const float* W2_w   = (const float*)d_in[17];
  const float* W2_b   = (const float*)d_in[18];
  const float* lin_w  = (const float*)d_in[19];
  const float* lin_b  = (const float*)d_in[20];

  char* scr = (char*)d_out;
  float* emb_enc = (float*)(scr + 0);
  float* emb_dec = (float*)(scr + 4194304);
  float* gi_f    = (float*)(scr + 6291456);
  float* gi_b    = (float*)(scr + 18874368);
  float* gi_dx   = (float*)(scr + 31457280);
  float* enc     = (float*)(scr + 37748736);
  float* projf   = (float*)(scr + 46137344);
  unsigned short* whf_bf = (unsigned short*)(scr + 58720256);
  unsigned short* whb_bf = (unsigned short*)(scr + 59113472);
  unsigned short* whd_bf = (unsigned short*)(scr + 59506688);
  unsigned short* encw2  = (unsigned short*)(scr + 59899904);
  unsigned short* projt  = (unsigned short*)(scr + 61997056);
  float* encb2 = (float*)(scr + 68288512);
  int*   sizes = (int*)(scr + 68304896);
  float* h0    = (float*)(scr + 68305024);
  float* hbufE = (float*)(scr + 71303168);   // 131072
  float* hbufD = (float*)(scr + 71434240);   // 65536
  int*   flagE = (int*)  (scr + 71499776);   // 24576
  int*   flagD = (int*)  (scr + 71524352);   // 12288

  unsigned short* outs_bf = (unsigned short*)d_ws;
  unsigned short* lin_bf  = (unsigned short*)((char*)d_ws + (1<<20));
  const bool big = ws_size >= (size_t)(1<<20) + 16384000u + 1024u;

  hipFuncSetAttribute((const void*)k_encoder, hipFuncAttributeMaxDynamicSharedMemorySize, 135232);
  hipFuncSetAttribute((const void*)k_decoder, hipFuncAttributeMaxDynamicSharedMemorySize, 137312);

  // zero the exchange flags (fresh stamps every call -> deterministic)
  hipMemsetAsync(scr + 71499776, 0, 24576 + 12288, stream);

  k_sizes<<<1, 32, 0, stream>>>(enc_in, sizes);
  k_gather<<<Bb*TEe, 256, 0, stream>>>(enc_in, embW, emb_enc, Bb*TEe);
  k_gather<<<Bb*TDd, 256, 0, stream>>>(dec_in, embW, emb_dec, Bb*TDd);
  k_chunkw<<<768, 256, 0, stream>>>(Wh_f, whf_bf, 768);
  k_chunkw<<<768, 256, 0, stream>>>(Wh_b, whb_bf, 768);
  k_chunkw<<<768, 256, 0, stream>>>(Wh_d, whd_bf, 768);
  if (big) k_extract_bf16<<<32000, 256, 0, stream>>>(lin_w, lin_bf, 32000*256);

  k_gemm<false,false,false,false><<<dim3(6,32), 256, 0, stream>>>(
      emb_enc, Wi_f, bi_f, gi_f, 4096, 768, 256, 256, 256, 768);
  k_gemm<false,false,false,false><<<dim3(6,32), 256, 0, stream>>>(
      emb_enc, Wi_b, bi_b, gi_b, 4096, 768, 256, 256, 256, 768);
  k_gemm<false,false,false,false><<<dim3(6,16), 256, 0, stream>>>(
      emb_dec, Wi_d + 512, bi_d, gi_dx, 2048, 768, 256, 256, 768, 768);

  k_encoder<<<192, 768, 135232, stream>>>(whf_bf, whb_bf, bh_f, bh_b, gi_f, gi_b,
                                          enc, hbufE, flagE);
  k_encb2<<<Bb*TEe, 64, 0, stream>>>(enc, W2_b, encb2);

  k_gemm<false,false,true,true><<<dim3(2,32), 256, 0, stream>>>(
      enc, W2_w, nullptr, encw2, 4096, 256, 512, 512, 256, 256);
  k_gemm<false,false,false,false><<<dim3(6,32), 256, 0, stream>>>(
      enc, Wi_d, nullptr, projf, 4096, 768, 512, 512, 768, 768);
  k_projchunk<<<(Bb*16*768*8)/256, 256, 0, stream>>>(projf, projt);
  k_hinit<<<Bb, 256, 0, stream>>>(enc, sizes, W1_w, W1_b, h0);

  k_decoder<<<96, 768, 137312, stream>>>(whd_bf, bh_d, gi_dx, encw2, encb2, projt,
                                         h0, outs_bf, hbufD, flagD);

  if (big)
    k_gemm<true,true,false,false><<<dim3(250,16), 256, 0, stream>>>(
        outs_bf, lin_bf, lin_b, d_out, 2048, 32000, 256, 256, 256, 32000);
  else
    k_gemm<true,false,false,false><<<dim3(250,16), 256, 0, stream>>>(
        outs_bf, lin_w, lin_b, d_out, 2048, 32000, 256, 256, 256, 32000);
}

// Round 10
// 2206.405 us; speedup vs baseline: 1.7840x; 1.7840x over previous
//
#include <hip/hip_runtime.h>
#include <hip/hip_bf16.h>

#define Vv 32000
#define Ee 256
#define Hh 256
#define Bb 32
#define TEe 128
#define TDd 64

typedef __attribute__((ext_vector_type(4))) float f32x4;
typedef __attribute__((ext_vector_type(8))) short short8;
typedef __attribute__((ext_vector_type(2))) unsigned int uint2v;
typedef __attribute__((ext_vector_type(4))) unsigned int uint4v;

static __device__ __forceinline__ unsigned short f2bf(float f){
  unsigned u = __float_as_uint(f);
  u += 0x7fffu + ((u >> 16) & 1u);           // round-to-nearest-even
  return (unsigned short)(u >> 16);
}
static __device__ __forceinline__ unsigned pack2(float a, float b){
  return ((unsigned)f2bf(b) << 16) | (unsigned)f2bf(a);
}
// dot of 8 packed bf16 (uint4) with 8 f32
static __device__ __forceinline__ float dot8(uint4v u, const float* hh){
  float s = 0.f;
  #pragma unroll
  for (int i = 0; i < 4; ++i){
    unsigned w = u[i];
    s = fmaf(__uint_as_float(w << 16),        hh[2*i],   s);
    s = fmaf(__uint_as_float(w & 0xffff0000u), hh[2*i+1], s);
  }
  return s;
}
static __device__ __forceinline__ float sigmoidf_(float x){
  return 1.f / (1.f + __expf(-x));
}

// ---------------- small prep kernels ----------------
__global__ void k_sizes(const int* __restrict__ enc_in, int* __restrict__ sizes){
  int b = threadIdx.x;
  if (b < Bb){
    int c = 0;
    for (int t = 0; t < TEe; ++t) c += (enc_in[b*TEe + t] > 0);
    sizes[b] = c;
  }
}

__global__ void k_gather(const int* __restrict__ tok, const float* __restrict__ embW,
                         float* __restrict__ out, int rows){
  int i = blockIdx.x * 256 + threadIdx.x;
  int r = i >> 8, c = i & 255;
  if (r < rows) out[i] = embW[(size_t)tok[r]*Ee + c];
}

// f32 -> bf16 row-major
__global__ void k_extract_bf16(const float* __restrict__ src, unsigned short* __restrict__ dst,
                               int n){
  int i = blockIdx.x * 256 + threadIdx.x;
  if (i < n) dst[i] = f2bf(src[i]);
}

// f32 [rows][256] -> chunked bf16 [32][rows][8]  (kb-major for coalesced staging)
__global__ void k_chunkw(const float* __restrict__ src, unsigned short* __restrict__ dst, int rows){
  int idx = blockIdx.x * 256 + threadIdx.x;
  if (idx < rows * 256){
    int i = idx & 7, r = (idx >> 3) % rows, kb = idx / (rows * 8);
    dst[idx] = f2bf(src[(size_t)r*256 + kb*8 + i]);
  }
}

// projf f32 [B*TE][768] -> chunked bf16 [B][16][768][8]
__global__ void k_projchunk(const float* __restrict__ in, unsigned short* __restrict__ out){
  int idx = blockIdx.x * 256 + threadIdx.x;     // total B*16*768*8
  int i = idx & 7;
  int t1 = idx >> 3;
  int n = t1 % 768;
  int t2 = t1 / 768;
  int kb = t2 & 15, b = t2 >> 4;
  out[idx] = f2bf(in[(size_t)(b*TEe + kb*8 + i)*768 + n]);
}

// ---------------- bf16 MFMA GEMM: C[M,N] = A[M,K] * B^T + bias ----------------
template<bool A_BF16, bool B_BF16, bool B_KMAJOR, bool OUT_BF16>
__global__ __launch_bounds__(256) void k_gemm(
  const void* __restrict__ Av, const void* __restrict__ Bv,
  const float* __restrict__ bias, void* __restrict__ Cv,
  int M, int N, int K, int lda, int ldb, int ldc)
{
  __shared__ unsigned short lA[128*40];
  __shared__ unsigned short lB[128*40];
  const int tid  = threadIdx.x;
  const int lane = tid & 63;
  const int w = tid >> 6, wr = w >> 1, wc = w & 1;
  const int m0 = blockIdx.y * 128, n0 = blockIdx.x * 128;
  f32x4 acc[4][4];
  #pragma unroll
  for (int i = 0; i < 4; ++i)
    #pragma unroll
    for (int j = 0; j < 4; ++j) acc[i][j] = (f32x4){0.f,0.f,0.f,0.f};

  for (int k0 = 0; k0 < K; k0 += 32){
    if (A_BF16){
      const unsigned short* A = (const unsigned short*)Av;
      #pragma unroll
      for (int it = 0; it < 2; ++it){
        int idx = tid + it*256; int r = idx >> 2, q = idx & 3;
        *(uint4v*)&lA[r*40 + q*8] = *(const uint4v*)(A + (size_t)(m0+r)*lda + k0 + q*8);
      }
    } else {
      const float* A = (const float*)Av;
      #pragma unroll
      for (int it = 0; it < 4; ++it){
        int idx = tid + it*256; int r = idx >> 3, q = idx & 7;
        f32x4 v = *(const f32x4*)(A + (size_t)(m0+r)*lda + k0 + q*4);
        uint2v pk; pk[0] = pack2(v[0], v[1]); pk[1] = pack2(v[2], v[3]);
        *(uint2v*)&lA[r*40 + q*4] = pk;
      }
    }
    if (B_KMAJOR){
      const float* Bp = (const float*)Bv;
      #pragma unroll
      for (int it = 0; it < 4; ++it){
        int idx = tid + it*256; int kk = idx >> 5, nq = idx & 31;
        f32x4 v = *(const f32x4*)(Bp + (size_t)(k0+kk)*ldb + n0 + nq*4);
        #pragma unroll
        for (int s2 = 0; s2 < 4; ++s2) lB[(nq*4+s2)*40 + kk] = f2bf(v[s2]);
      }
    } else if (B_BF16){
      const unsigned short* Bp = (const unsigned short*)Bv;
      #pragma unroll
      for (int it = 0; it < 2; ++it){
        int idx = tid + it*256; int r = idx >> 2, q = idx & 3;
        *(uint4v*)&lB[r*40 + q*8] = *(const uint4v*)(Bp + (size_t)(n0+r)*ldb + k0 + q*8);
      }
    } else {
      const float* Bp = (const float*)Bv;
      #pragma unroll
      for (int it = 0; it < 4; ++it){
        int idx = tid + it*256; int r = idx >> 3, q = idx & 7;
        f32x4 v = *(const f32x4*)(Bp + (size_t)(n0+r)*ldb + k0 + q*4);
        uint2v pk; pk[0] = pack2(v[0], v[1]); pk[1] = pack2(v[2], v[3]);
        *(uint2v*)&lB[r*40 + q*4] = pk;
      }
    }
    __syncthreads();
    short8 av[4], bv[4];
    #pragma unroll
    for (int i = 0; i < 4; ++i)
      av[i] = *(const short8*)&lA[(wr*64 + i*16 + (lane&15))*40 + (lane>>4)*8];
    #pragma unroll
    for (int j = 0; j < 4; ++j)
      bv[j] = *(const short8*)&lB[(wc*64 + j*16 + (lane&15))*40 + (lane>>4)*8];
    #pragma unroll
    for (int i = 0; i < 4; ++i)
      #pragma unroll
      for (int j = 0; j < 4; ++j)
        acc[i][j] = __builtin_amdgcn_mfma_f32_16x16x32_bf16(av[i], bv[j], acc[i][j], 0, 0, 0);
    __syncthreads();
  }
  #pragma unroll
  for (int i = 0; i < 4; ++i){
    #pragma unroll
    for (int j = 0; j < 4; ++j){
      int col = n0 + wc*64 + j*16 + (lane & 15);
      float bb = bias ? bias[col] : 0.f;
      #pragma unroll
      for (int r = 0; r < 4; ++r){
        int row = m0 + wr*64 + i*16 + (lane>>4)*4 + r;
        float v = acc[i][j][r] + bb;
        if (OUT_BF16) ((unsigned short*)Cv)[(size_t)row*ldc + col] = f2bf(v);
        else          ((float*)Cv)[(size_t)row*ldc + col] = v;
      }
    }
  }
}

// ---------------- encoder recurrence: 64 blocks = (dir, batch), 1024 threads ----------------
// (R7 structure, measured ~4.2us/step: rows 0-255 LDS, rows 256-767 streamed-coalesced.)
__global__ __launch_bounds__(1024) void k_encoder(
  const unsigned short* __restrict__ Whf, const unsigned short* __restrict__ Whb,
  const float* __restrict__ bhf, const float* __restrict__ bhb,
  const float* __restrict__ gif, const float* __restrict__ gib,
  float* __restrict__ encoded)
{
  extern __shared__ char smem[];
  unsigned short* lw = (unsigned short*)smem;        // 131072
  float* hA   = (float*)(smem + 131072);             // 1024
  float* hB   = (float*)(smem + 132096);             // 1024
  float* parA = (float*)(smem + 133120);             // 4096
  float* parB = (float*)(smem + 137216);             // 4096
  const int dir = blockIdx.x & 1, b = blockIdx.x >> 1;
  const unsigned short* Wh = dir ? Whb : Whf;
  const float* bh = dir ? bhb : bhf;
  const float* gi = dir ? gib : gif;
  const int T = threadIdx.x;
  const int rl = T & 255, q4 = T >> 8;
  const int rrh = T & 511, hf = T >> 9;
  for (int cc = T; cc < 256*32; cc += 1024){
    int r = cc >> 5, q = cc & 31;
    *(uint4v*)&lw[(r*32 + (q ^ (r & 31)))*8] = *(const uint4v*)(Wh + (size_t)q*6144 + r*8);
  }
  uint4v wr_[16];
  #pragma unroll
  for (int q = 0; q < 16; ++q)
    wr_[q] = *(const uint4v*)(Wh + (size_t)(hf*16 + q)*6144 + (256 + rrh)*8);
  float bh0 = 0.f, bh1 = 0.f, bh2 = 0.f;
  if (T < 256){ bh0 = bh[T]; bh1 = bh[T+256]; bh2 = bh[T+512]; hA[T] = 0.f; }
  __syncthreads();
  const float* hc = hA; float* hn = hB;
  for (int s = 0; s < TEe; ++s){
    const int t = dir ? (TEe-1-s) : s;
    float aL = 0.f;
    #pragma unroll
    for (int i = 0; i < 8; ++i){
      const int ck = q4*8 + i;
      float hr[8];
      *(f32x4*)&hr[0] = *(const f32x4*)&hc[ck*8];
      *(f32x4*)&hr[4] = *(const f32x4*)&hc[ck*8+4];
      aL += dot8(*(const uint4v*)&lw[(rl*32 + (ck ^ (rl & 31)))*8], hr);
    }
    parA[q4*256 + rl] = aL;
    float aR = 0.f;
    const float* hh = hc + hf*128;
    #pragma unroll
    for (int q = 0; q < 16; ++q){
      float hr[8];
      *(f32x4*)&hr[0] = *(const f32x4*)&hh[q*8];
      *(f32x4*)&hr[4] = *(const f32x4*)&hh[q*8+4];
      aR += dot8(wr_[q], hr);
    }
    parB[hf*512 + rrh] = aR;
    __syncthreads();                   // B1: partials ready
    if (T < 256){
      const int j = T;
      const float* grow = gi + (size_t)(b*TEe + t)*768;
      const float A0 = parA[j] + parA[256+j] + parA[512+j] + parA[768+j] + bh0;
      const float A1 = parB[j] + parB[512+j] + bh1;
      const float A2 = parB[256+j] + parB[768+j] + bh2;
      const float r = sigmoidf_(grow[j] + A0);
      const float z = sigmoidf_(grow[j+256] + A1);
      const float n = tanhf(grow[j+512] + r*A2);
      const float hnew = (1.f - z)*n + z*hc[j];
      hn[j] = hnew;
      encoded[(size_t)(b*TEe + t)*512 + dir*256 + j] = hnew;
    }
    __syncthreads();                   // B2: h_new visible
    const float* tmp = hc; hc = hn; hn = (float*)tmp;
  }
}

// encb2[r] = encoded[r,:512] . W2_b
__global__ void k_encb2(const float* __restrict__ encoded, const float* __restrict__ W2b,
                        float* __restrict__ encb2){
  int r = blockIdx.x, l = threadIdx.x;
  const float* e = encoded + (size_t)r*512;
  float s = 0.f;
  for (int k = l; k < 512; k += 64) s += e[k]*W2b[k];
  for (int off = 32; off; off >>= 1) s += __shfl_down(s, off);
  if (l == 0) encb2[r] = s;
}

__global__ void k_hinit(const float* __restrict__ encoded, const int* __restrict__ sizes,
                        const float* __restrict__ W1w, const float* __restrict__ W1b,
                        float* __restrict__ h0){
  int b = blockIdx.x, o = threadIdx.x;
  int idx = sizes[b] - 1;
  idx = idx < 0 ? 0 : (idx > TEe-1 ? TEe-1 : idx);
  const float* ls = encoded + (size_t)(b*TEe + idx)*512;
  const float* wv = W1w + (size_t)o*512;
  float s = W1b[o];
  for (int k = 0; k < 512; k += 4){
    f32x4 a = *(const f32x4*)(ls + k);
    f32x4 w4 = *(const f32x4*)(wv + k);
    s = fmaf(a[0],w4[0], fmaf(a[1],w4[1], fmaf(a[2],w4[2], fmaf(a[3],w4[3], s))));
  }
  h0[b*256 + o] = s;
}

// ---------------- decoder: 32 blocks = batch, 1024 threads, wave-specialized ----------------
// Pipeline per step: gates -> B1 -> 3 segments where
//   group A (thr 0-767):   dots a[j]=Whd[j].h_t for step t+1 (rows<DNR from LDS,
//                          rest streamed coalesced; acc in register across segments)
//   group B (thr 768-1023): seg1 scores (encw2 LDS-resident) / seg2 softmax /
//                          seg3 ctx-projection (projt streamed)
// Both feed gates(t+1). n-gate: ctx (gcs) stays OUTSIDE the r* product.
#define DNR 160
__global__ __launch_bounds__(1024) void k_decoder(
  const unsigned short* __restrict__ Whd, const float* __restrict__ bhd,
  const float* __restrict__ gidx,            // [B][TD][768] f32 (includes bi_d)
  const unsigned short* __restrict__ encw2,  // [B*TE][256] bf16
  const float* __restrict__ encb2,           // [B*TE]
  const unsigned short* __restrict__ projt,  // [B][16][768][8] bf16
  const float* __restrict__ h0,
  unsigned short* __restrict__ outs_bf)      // [B][TD][256] bf16
{
  extern __shared__ char smem[];
  unsigned short* le = (unsigned short*)smem;            // 65536
  unsigned short* lw = (unsigned short*)(smem + 65536);  // DNR*512 = 81920
  float* h   = (float*)(smem + 147456);                  // 1024
  float* par = (float*)(smem + 148480);                  // 3072
  float* gcs = (float*)(smem + 151552);                  // 3072
  float* p   = (float*)(smem + 154624);                  // 512
  float* ebl = (float*)(smem + 155136);                  // 512  -> total 155648
  const int b = blockIdx.x, T = threadIdx.x;
  // stage encw2[b] (rows XOR-swizzled by k-chunk)
  for (int cc = T; cc < 128*32; cc += 1024){
    int r = cc >> 5, q = cc & 31;
    *(uint4v*)&le[(r*32 + (q ^ (r & 31)))*8] =
        *(const uint4v*)(encw2 + ((size_t)(b*TEe + r) << 8) + (q << 3));
  }
  // stage Whd rows [0,DNR)
  for (int cc = T; cc < DNR*32; cc += 1024){
    int r = cc >> 5, q = cc & 31;
    *(uint4v*)&lw[(r*32 + (q ^ (r & 31)))*8] =
        *(const uint4v*)(Whd + (size_t)q*6144 + r*8);
  }
  for (int i = T; i < 256; i += 1024) h[i] = h0[b*256 + i];
  for (int i = T; i < 768; i += 1024) gcs[i] = 0.f;      // ctx_init = 0
  if (T < TEe) ebl[T] = encb2[b*TEe + T];
  float bh0 = 0.f, bh1 = 0.f, bh2 = 0.f;
  if (T < 256){ bh0 = bhd[T]; bh1 = bhd[T+256]; bh2 = bhd[T+512]; }
  const unsigned short* ptc = projt + (size_t)b*98304;
  __syncthreads();
  // prologue: dots on h0 + g-regs for t=0
  float g0 = 0.f, g1 = 0.f, g2 = 0.f;
  if (T < 256){
    const float* grow = gidx + (size_t)(b*TDd)*768;
    g0 = grow[T]; g1 = grow[T+256]; g2 = grow[T+512];
  }
  float acc = 0.f;
  if (T < 768){
    if (T < DNR){
      const unsigned short* lwr = lw + T*256;
      #pragma unroll
      for (int q = 0; q < 32; ++q){
        float hr[8];
        *(f32x4*)&hr[0] = *(const f32x4*)&h[q*8];
        *(f32x4*)&hr[4] = *(const f32x4*)&h[q*8+4];
        acc += dot8(*(const uint4v*)(lwr + ((q ^ (T & 31)) << 3)), hr);
      }
    } else {
      #pragma unroll
      for (int q = 0; q < 32; ++q){
        float hr[8];
        *(f32x4*)&hr[0] = *(const f32x4*)&h[q*8];
        *(f32x4*)&hr[4] = *(const f32x4*)&h[q*8+4];
        acc += dot8(*(const uint4v*)(Whd + (size_t)q*6144 + T*8), hr);
      }
    }
    par[T] = acc;
  }
  __syncthreads();
  for (int t = 0; t < TDd; ++t){
    // gates: h_t from dots(par), ctx(gcs), gi(g-regs)
    if (T < 256){
      const float A0 = par[T] + bh0;
      const float A1 = par[T+256] + bh1;
      const float A2 = par[T+512] + bh2;
      const float r = sigmoidf_(g0 + gcs[T] + A0);
      const float z = sigmoidf_(g1 + gcs[T+256] + A1);
      const float n = tanhf(g2 + gcs[T+512] + r*A2);
      const float hnew = (1.f - z)*n + z*h[T];
      h[T] = hnew;
      outs_bf[(size_t)(b*TDd + t)*256 + T] = f2bf(hnew);
    }
    if (t + 1 == TDd) break;
    __syncthreads();                   // B1: h_t visible
    acc = 0.f;
    // ---- seg1: A dots q=[0,11) + gi prefetch ; B scores ----
    if (T < 768){
      if (T < 256){
        const float* grow = gidx + (size_t)(b*TDd + t + 1)*768;
        g0 = grow[T]; g1 = grow[T+256]; g2 = grow[T+512];
      }
      if (T < DNR){
        const unsigned short* lwr = lw + T*256;
        #pragma unroll
        for (int q = 0; q < 11; ++q){
          float hr[8];
          *(f32x4*)&hr[0] = *(const f32x4*)&h[q*8];
          *(f32x4*)&hr[4] = *(const f32x4*)&h[q*8+4];
          acc += dot8(*(const uint4v*)(lwr + ((q ^ (T & 31)) << 3)), hr);
        }
      } else {
        #pragma unroll
        for (int q = 0; q < 11; ++q){
          float hr[8];
          *(f32x4*)&hr[0] = *(const f32x4*)&h[q*8];
          *(f32x4*)&hr[4] = *(const f32x4*)&h[q*8+4];
          acc += dot8(*(const uint4v*)(Whd + (size_t)q*6144 + T*8), hr);
        }
      }
    } else {
      const int i = T - 768, pos = i >> 1, kh = i & 1;
      const unsigned short* er = le + pos*256;
      float s = 0.f;
      #pragma unroll
      for (int ii = 0; ii < 16; ++ii){
        const int q = kh*16 + ii;
        float hr[8];
        *(f32x4*)&hr[0] = *(const f32x4*)&h[q*8];
        *(f32x4*)&hr[4] = *(const f32x4*)&h[q*8+4];
        s += dot8(*(const uint4v*)(er + ((q ^ (pos & 31)) << 3)), hr);
      }
      s += __shfl_xor(s, 1);
      if (kh == 0) p[pos] = s + ebl[pos];
    }
    __syncthreads();                   // B2: p_raw ready
    // ---- seg2: A dots q=[11,22) ; B softmax (wave 12) ----
    if (T < 768){
      if (T < DNR){
        const unsigned short* lwr = lw + T*256;
        #pragma unroll
        for (int q = 11; q < 22; ++q){
          float hr[8];
          *(f32x4*)&hr[0] = *(const f32x4*)&h[q*8];
          *(f32x4*)&hr[4] = *(const f32x4*)&h[q*8+4];
          acc += dot8(*(const uint4v*)(lwr + ((q ^ (T & 31)) << 3)), hr);
        }
      } else {
        #pragma unroll
        for (int q = 11; q < 22; ++q){
          float hr[8];
          *(f32x4*)&hr[0] = *(const f32x4*)&h[q*8];
          *(f32x4*)&hr[4] = *(const f32x4*)&h[q*8+4];
          acc += dot8(*(const uint4v*)(Whd + (size_t)q*6144 + T*8), hr);
        }
      }
    } else if (T < 832){
      const int l = T - 768;
      float m = fmaxf(p[l], p[l+64]);
      for (int off = 32; off; off >>= 1) m = fmaxf(m, __shfl_xor(m, off));
      float e0 = __expf(p[l] - m), e1 = __expf(p[l+64] - m);
      float ss = e0 + e1;
      for (int off = 32; off; off >>= 1) ss += __shfl_xor(ss, off);
      float inv = 1.f / ss;
      p[l] = e0*inv; p[l+64] = e1*inv;
    }
    __syncthreads();                   // B3: softmax done
    // ---- seg3: A dots q=[22,32) -> par ; B ctx projection -> gcs ----
    if (T < 768){
      if (T < DNR){
        const unsigned short* lwr = lw + T*256;
        #pragma unroll
        for (int q = 22; q < 32; ++q){
          float hr[8];
          *(f32x4*)&hr[0] = *(const f32x4*)&h[q*8];
          *(f32x4*)&hr[4] = *(const f32x4*)&h[q*8+4];
          acc += dot8(*(const uint4v*)(lwr + ((q ^ (T & 31)) << 3)), hr);
        }
      } else {
        #pragma unroll
        for (int q = 22; q < 32; ++q){
          float hr[8];
          *(f32x4*)&hr[0] = *(const f32x4*)&h[q*8];
          *(f32x4*)&hr[4] = *(const f32x4*)&h[q*8+4];
          acc += dot8(*(const uint4v*)(Whd + (size_t)q*6144 + T*8), hr);
        }
      }
      par[T] = acc;
    } else {
      const int i = T - 768;
      float c0 = 0.f, c1 = 0.f, c2 = 0.f;
      #pragma unroll
      for (int q = 0; q < 16; ++q){
        float pr[8];
        *(f32x4*)&pr[0] = *(const f32x4*)&p[q*8];
        *(f32x4*)&pr[4] = *(const f32x4*)&p[q*8+4];
        const unsigned short* base = ptc + (size_t)q*6144;
        c0 += dot8(*(const uint4v*)(base + i*8), pr);
        c1 += dot8(*(const uint4v*)(base + (i+256)*8), pr);
        c2 += dot8(*(const uint4v*)(base + (i+512)*8), pr);
      }
      gcs[i] = c0; gcs[i+256] = c1; gcs[i+512] = c2;
    }
    __syncthreads();                   // B4: par + gcs ready for next gates
  }
}

extern "C" void kernel_launch(void* const* d_in, const int* in_sizes, int n_in,
                              void* d_out, int out_size, void* d_ws, size_t ws_size,
                              hipStream_t stream)
{
  (void)in_sizes; (void)n_in; (void)out_size;
  const int*   enc_in = (const int*)d_in[0];
  const int*   dec_in = (const int*)d_in[1];
  const float* embW   = (const float*)d_in[2];
  const float* Wi_f   = (const float*)d_in[3];
  const float* Wh_f   = (const float*)d_in[4];
  const float* bi_f   = (const float*)d_in[5];
  const float* bh_f   = (const float*)d_in[6];
  const float* Wi_b   = (const float*)d_in[7];
  const float* Wh_b   = (const float*)d_in[8];
  const float* bi_b   = (const float*)d_in[9];
  const float* bh_b   = (const float*)d_in[10];
  const float* Wi_d   = (const float*)d_in[11];
  const float* Wh_d   = (const float*)d_in[12];
  const float* bi_d   = (const float*)d_in[13];
  const float* bh_d   = (const float*)d_in[14];
  const float* W1_w   = (const float*)d_in[15];
  const float* W1_b   = (const float*)d_in[16];
  const float* W2_w   = (const float*)d_in[17];
  const float* W2_b   = (const float*)d_in[18];
  const float* lin_w  = (const float*)d_in[19];
  const float* lin_b  = (const float*)d_in[20];

  char* scr = (char*)d_out;
  float* emb_enc = (float*)(scr + 0);
  float* emb_dec = (float*)(scr + 4194304);
  float* gi_f    = (float*)(scr + 6291456);
  float* gi_b    = (float*)(scr + 18874368);
  float* gi_dx   = (float*)(scr + 31457280);
  float* enc     = (float*)(scr + 37748736);
  float* projf   = (float*)(scr + 46137344);
  unsigned short* whf_bf = (unsigned short*)(scr + 58720256);
  unsigned short* whb_bf = (unsigned short*)(scr + 59113472);
  unsigned short* whd_bf = (unsigned short*)(scr + 59506688);
  unsigned short* encw2  = (unsigned short*)(scr + 59899904);
  unsigned short* projt  = (unsigned short*)(scr + 61997056);
  float* encb2 = (float*)(scr + 68288512);
  int*   sizes = (int*)(scr + 68304896);
  float* h0    = (float*)(scr + 68305024);

  unsigned short* outs_bf = (unsigned short*)d_ws;
  unsigned short* lin_bf  = (unsigned short*)((char*)d_ws + (1<<20));
  const bool big = ws_size >= (size_t)(1<<20) + 16384000u + 1024u;

  // allow >64KB dynamic LDS (capture-safe host attribute; idempotent)
  hipFuncSetAttribute((const void*)k_encoder, hipFuncAttributeMaxDynamicSharedMemorySize, 141312);
  hipFuncSetAttribute((const void*)k_decoder, hipFuncAttributeMaxDynamicSharedMemorySize, 155648);

  k_sizes<<<1, 32, 0, stream>>>(enc_in, sizes);
  k_gather<<<Bb*TEe, 256, 0, stream>>>(enc_in, embW, emb_enc, Bb*TEe);
  k_gather<<<Bb*TDd, 256, 0, stream>>>(dec_in, embW, emb_dec, Bb*TDd);
  k_chunkw<<<768, 256, 0, stream>>>(Wh_f, whf_bf, 768);
  k_chunkw<<<768, 256, 0, stream>>>(Wh_b, whb_bf, 768);
  k_chunkw<<<768, 256, 0, stream>>>(Wh_d, whd_bf, 768);
  if (big) k_extract_bf16<<<32000, 256, 0, stream>>>(lin_w, lin_bf, 32000*256);

  k_gemm<false,false,false,false><<<dim3(6,32), 256, 0, stream>>>(
      emb_enc, Wi_f, bi_f, gi_f, 4096, 768, 256, 256, 256, 768);
  k_gemm<false,false,false,false><<<dim3(6,32), 256, 0, stream>>>(
      emb_enc, Wi_b, bi_b, gi_b, 4096, 768, 256, 256, 256, 768);
  k_gemm<false,false,false,false><<<dim3(6,16), 256, 0, stream>>>(
      emb_dec, Wi_d + 512, bi_d, gi_dx, 2048, 768, 256, 256, 768, 768);

  k_encoder<<<64, 1024, 141312, stream>>>(whf_bf, whb_bf, bh_f, bh_b, gi_f, gi_b, enc);
  k_encb2<<<Bb*TEe, 64, 0, stream>>>(enc, W2_b, encb2);

  k_gemm<false,false,true,true><<<dim3(2,32), 256, 0, stream>>>(
      enc, W2_w, nullptr, encw2, 4096, 256, 512, 512, 256, 256);
  k_gemm<false,false,false,false><<<dim3(6,32), 256, 0, stream>>>(
      enc, Wi_d, nullptr, projf, 4096, 768, 512, 512, 768, 768);
  k_projchunk<<<(Bb*16*768*8)/256, 256, 0, stream>>>(projf, projt);
  k_hinit<<<Bb, 256, 0, stream>>>(enc, sizes, W1_w, W1_b, h0);

  k_decoder<<<Bb, 1024, 155648, stream>>>(whd_bf, bh_d, gi_dx, encw2, encb2, projt, h0, outs_bf);

  if (big)
    k_gemm<true,true,false,false><<<dim3(250,16), 256, 0, stream>>>(
        outs_bf, lin_bf, lin_b, d_out, 2048, 32000, 256, 256, 256, 32000);
  else
    k_gemm<true,false,false,false><<<dim3(250,16), 256, 0, stream>>>(
        outs_bf, lin_w, lin_b, d_out, 2048, 32000, 256, 256, 256, 32000);
}

// Round 11
// 2016.256 us; speedup vs baseline: 1.9522x; 1.0943x over previous
//
#include <hip/hip_runtime.h>
#include <hip/hip_bf16.h>

#define Vv 32000
#define Ee 256
#define Hh 256
#define Bb 32
#define TEe 128
#define TDd 64

typedef __attribute__((ext_vector_type(4))) float f32x4;
typedef __attribute__((ext_vector_type(8))) short short8;
typedef __attribute__((ext_vector_type(2))) unsigned int uint2v;
typedef __attribute__((ext_vector_type(4))) unsigned int uint4v;

static __device__ __forceinline__ unsigned short f2bf(float f){
  unsigned u = __float_as_uint(f);
  u += 0x7fffu + ((u >> 16) & 1u);           // round-to-nearest-even
  return (unsigned short)(u >> 16);
}
static __device__ __forceinline__ unsigned pack2(float a, float b){
  return ((unsigned)f2bf(b) << 16) | (unsigned)f2bf(a);
}
// dot of 8 packed bf16 (uint4) with 8 f32
static __device__ __forceinline__ float dot8(uint4v u, const float* hh){
  float s = 0.f;
  #pragma unroll
  for (int i = 0; i < 4; ++i){
    unsigned w = u[i];
    s = fmaf(__uint_as_float(w << 16),        hh[2*i],   s);
    s = fmaf(__uint_as_float(w & 0xffff0000u), hh[2*i+1], s);
  }
  return s;
}
static __device__ __forceinline__ float sigmoidf_(float x){
  return 1.f / (1.f + __expf(-x));
}

// ---------------- small prep kernels ----------------
__global__ void k_sizes(const int* __restrict__ enc_in, int* __restrict__ sizes){
  int b = threadIdx.x;
  if (b < Bb){
    int c = 0;
    for (int t = 0; t < TEe; ++t) c += (enc_in[b*TEe + t] > 0);
    sizes[b] = c;
  }
}

__global__ void k_gather(const int* __restrict__ tok, const float* __restrict__ embW,
                         float* __restrict__ out, int rows){
  int i = blockIdx.x * 256 + threadIdx.x;
  int r = i >> 8, c = i & 255;
  if (r < rows) out[i] = embW[(size_t)tok[r]*Ee + c];
}

// f32 -> bf16 row-major
__global__ void k_extract_bf16(const float* __restrict__ src, unsigned short* __restrict__ dst,
                               int n){
  int i = blockIdx.x * 256 + threadIdx.x;
  if (i < n) dst[i] = f2bf(src[i]);
}

// f32 [rows][256] -> chunked bf16 [32][rows][8]  (kb-major for coalesced staging)
__global__ void k_chunkw(const float* __restrict__ src, unsigned short* __restrict__ dst, int rows){
  int idx = blockIdx.x * 256 + threadIdx.x;
  if (idx < rows * 256){
    int i = idx & 7, r = (idx >> 3) % rows, kb = idx / (rows * 8);
    dst[idx] = f2bf(src[(size_t)r*256 + kb*8 + i]);
  }
}

// projf f32 [B*TE][768] -> chunked bf16 [B][16][768][8]
__global__ void k_projchunk(const float* __restrict__ in, unsigned short* __restrict__ out){
  int idx = blockIdx.x * 256 + threadIdx.x;     // total B*16*768*8
  int i = idx & 7;
  int t1 = idx >> 3;
  int n = t1 % 768;
  int t2 = t1 / 768;
  int kb = t2 & 15, b = t2 >> 4;
  out[idx] = f2bf(in[(size_t)(b*TEe + kb*8 + i)*768 + n]);
}

// ---------------- bf16 MFMA GEMM: C[M,N] = A[M,K] * B^T + bias ----------------
template<bool A_BF16, bool B_BF16, bool B_KMAJOR, bool OUT_BF16>
__global__ __launch_bounds__(256) void k_gemm(
  const void* __restrict__ Av, const void* __restrict__ Bv,
  const float* __restrict__ bias, void* __restrict__ Cv,
  int M, int N, int K, int lda, int ldb, int ldc)
{
  __shared__ unsigned short lA[128*40];
  __shared__ unsigned short lB[128*40];
  const int tid  = threadIdx.x;
  const int lane = tid & 63;
  const int w = tid >> 6, wr = w >> 1, wc = w & 1;
  const int m0 = blockIdx.y * 128, n0 = blockIdx.x * 128;
  f32x4 acc[4][4];
  #pragma unroll
  for (int i = 0; i < 4; ++i)
    #pragma unroll
    for (int j = 0; j < 4; ++j) acc[i][j] = (f32x4){0.f,0.f,0.f,0.f};

  for (int k0 = 0; k0 < K; k0 += 32){
    if (A_BF16){
      const unsigned short* A = (const unsigned short*)Av;
      #pragma unroll
      for (int it = 0; it < 2; ++it){
        int idx = tid + it*256; int r = idx >> 2, q = idx & 3;
        *(uint4v*)&lA[r*40 + q*8] = *(const uint4v*)(A + (size_t)(m0+r)*lda + k0 + q*8);
      }
    } else {
      const float* A = (const float*)Av;
      #pragma unroll
      for (int it = 0; it < 4; ++it){
        int idx = tid + it*256; int r = idx >> 3, q = idx & 7;
        f32x4 v = *(const f32x4*)(A + (size_t)(m0+r)*lda + k0 + q*4);
        uint2v pk; pk[0] = pack2(v[0], v[1]); pk[1] = pack2(v[2], v[3]);
        *(uint2v*)&lA[r*40 + q*4] = pk;
      }
    }
    if (B_KMAJOR){
      const float* Bp = (const float*)Bv;
      #pragma unroll
      for (int it = 0; it < 4; ++it){
        int idx = tid + it*256; int kk = idx >> 5, nq = idx & 31;
        f32x4 v = *(const f32x4*)(Bp + (size_t)(k0+kk)*ldb + n0 + nq*4);
        #pragma unroll
        for (int s2 = 0; s2 < 4; ++s2) lB[(nq*4+s2)*40 + kk] = f2bf(v[s2]);
      }
    } else if (B_BF16){
      const unsigned short* Bp = (const unsigned short*)Bv;
      #pragma unroll
      for (int it = 0; it < 2; ++it){
        int idx = tid + it*256; int r = idx >> 2, q = idx & 3;
        *(uint4v*)&lB[r*40 + q*8] = *(const uint4v*)(Bp + (size_t)(n0+r)*ldb + k0 + q*8);
      }
    } else {
      const float* Bp = (const float*)Bv;
      #pragma unroll
      for (int it = 0; it < 4; ++it){
        int idx = tid + it*256; int r = idx >> 3, q = idx & 7;
        f32x4 v = *(const f32x4*)(Bp + (size_t)(n0+r)*ldb + k0 + q*4);
        uint2v pk; pk[0] = pack2(v[0], v[1]); pk[1] = pack2(v[2], v[3]);
        *(uint2v*)&lB[r*40 + q*4] = pk;
      }
    }
    __syncthreads();
    short8 av[4], bv[4];
    #pragma unroll
    for (int i = 0; i < 4; ++i)
      av[i] = *(const short8*)&lA[(wr*64 + i*16 + (lane&15))*40 + (lane>>4)*8];
    #pragma unroll
    for (int j = 0; j < 4; ++j)
      bv[j] = *(const short8*)&lB[(wc*64 + j*16 + (lane&15))*40 + (lane>>4)*8];
    #pragma unroll
    for (int i = 0; i < 4; ++i)
      #pragma unroll
      for (int j = 0; j < 4; ++j)
        acc[i][j] = __builtin_amdgcn_mfma_f32_16x16x32_bf16(av[i], bv[j], acc[i][j], 0, 0, 0);
    __syncthreads();
  }
  #pragma unroll
  for (int i = 0; i < 4; ++i){
    #pragma unroll
    for (int j = 0; j < 4; ++j){
      int col = n0 + wc*64 + j*16 + (lane & 15);
      float bb = bias ? bias[col] : 0.f;
      #pragma unroll
      for (int r = 0; r < 4; ++r){
        int row = m0 + wr*64 + i*16 + (lane>>4)*4 + r;
        float v = acc[i][j][r] + bb;
        if (OUT_BF16) ((unsigned short*)Cv)[(size_t)row*ldc + col] = f2bf(v);
        else          ((float*)Cv)[(size_t)row*ldc + col] = v;
      }
    }
  }
}

// ---------------- encoder: 64 blocks = (dir, batch), 1024 threads ----------------
// Rows 0-255 in LDS; rows 256-767 streamed as half-rows with a DEPTH-8 register
// ring: use wb[q&7], immediately reload chunk q+8 (tail reloads next step's 0-7,
// so the ring stays warm across the step boundary). Weights are step-invariant,
// so prefetch never depends on h.
__global__ __launch_bounds__(1024) void k_encoder(
  const unsigned short* __restrict__ Whf, const unsigned short* __restrict__ Whb,
  const float* __restrict__ bhf, const float* __restrict__ bhb,
  const float* __restrict__ gif, const float* __restrict__ gib,
  float* __restrict__ encoded)
{
  extern __shared__ char smem[];
  unsigned short* lw = (unsigned short*)smem;        // 131072
  float* hA   = (float*)(smem + 131072);             // 1024
  float* hB   = (float*)(smem + 132096);             // 1024
  float* parA = (float*)(smem + 133120);             // 4096
  float* parB = (float*)(smem + 137216);             // 4096
  const int dir = blockIdx.x & 1, b = blockIdx.x >> 1;
  const unsigned short* Wh = dir ? Whb : Whf;
  const float* bh = dir ? bhb : bhf;
  const float* gi = dir ? gib : gif;
  const int T = threadIdx.x;
  const int rl = T & 255, q4 = T >> 8;
  const int rrh = T & 511, hf = T >> 9;
  const unsigned short* wsrc = Wh + (size_t)(hf*16)*6144 + (size_t)(256 + rrh)*8;
  uint4v wb[8];
  #pragma unroll
  for (int d = 0; d < 8; ++d) wb[d] = *(const uint4v*)(wsrc + (size_t)d*6144);
  for (int cc = T; cc < 256*32; cc += 1024){
    int r = cc >> 5, q = cc & 31;
    *(uint4v*)&lw[(r*32 + (q ^ (r & 31)))*8] = *(const uint4v*)(Wh + (size_t)q*6144 + r*8);
  }
  float bh0 = 0.f, bh1 = 0.f, bh2 = 0.f;
  if (T < 256){ bh0 = bh[T]; bh1 = bh[T+256]; bh2 = bh[T+512]; hA[T] = 0.f; }
  __syncthreads();
  const float* hc = hA; float* hn = hB;
  for (int s = 0; s < TEe; ++s){
    const int t = dir ? (TEe-1-s) : s;
    // LDS-part: quarter q4 of row rl
    float aL = 0.f;
    #pragma unroll
    for (int i = 0; i < 8; ++i){
      const int ck = q4*8 + i;
      float hr[8];
      *(f32x4*)&hr[0] = *(const f32x4*)&hc[ck*8];
      *(f32x4*)&hr[4] = *(const f32x4*)&hc[ck*8+4];
      aL += dot8(*(const uint4v*)&lw[(rl*32 + (ck ^ (rl & 31)))*8], hr);
    }
    parA[q4*256 + rl] = aL;
    // stream-part: half hf of row 256+rrh, depth-8 ring
    float aR = 0.f;
    const float* hh = hc + hf*128;
    #pragma unroll
    for (int q = 0; q < 16; ++q){
      float hr[8];
      *(f32x4*)&hr[0] = *(const f32x4*)&hh[q*8];
      *(f32x4*)&hr[4] = *(const f32x4*)&hh[q*8+4];
      aR += dot8(wb[q & 7], hr);
      wb[q & 7] = *(const uint4v*)(wsrc + (size_t)((q < 8) ? (q + 8) : (q - 8))*6144);
    }
    parB[hf*512 + rrh] = aR;
    __syncthreads();                   // B1: partials ready
    if (T < 256){
      const int j = T;
      const float* grow = gi + (size_t)(b*TEe + t)*768;
      const float A0 = parA[j] + parA[256+j] + parA[512+j] + parA[768+j] + bh0;
      const float A1 = parB[j] + parB[512+j] + bh1;
      const float A2 = parB[256+j] + parB[768+j] + bh2;
      const float r = sigmoidf_(grow[j] + A0);
      const float z = sigmoidf_(grow[j+256] + A1);
      const float n = tanhf(grow[j+512] + r*A2);
      const float hnew = (1.f - z)*n + z*hc[j];
      hn[j] = hnew;
      encoded[(size_t)(b*TEe + t)*512 + dir*256 + j] = hnew;
    }
    __syncthreads();                   // B2: h_new visible
    const float* tmp = hc; hc = hn; hn = (float*)tmp;
  }
}

// encb2[r] = encoded[r,:512] . W2_b
__global__ void k_encb2(const float* __restrict__ encoded, const float* __restrict__ W2b,
                        float* __restrict__ encb2){
  int r = blockIdx.x, l = threadIdx.x;
  const float* e = encoded + (size_t)r*512;
  float s = 0.f;
  for (int k = l; k < 512; k += 64) s += e[k]*W2b[k];
  for (int off = 32; off; off >>= 1) s += __shfl_down(s, off);
  if (l == 0) encb2[r] = s;
}

__global__ void k_hinit(const float* __restrict__ encoded, const int* __restrict__ sizes,
                        const float* __restrict__ W1w, const float* __restrict__ W1b,
                        float* __restrict__ h0){
  int b = blockIdx.x, o = threadIdx.x;
  int idx = sizes[b] - 1;
  idx = idx < 0 ? 0 : (idx > TEe-1 ? TEe-1 : idx);
  const float* ls = encoded + (size_t)(b*TEe + idx)*512;
  const float* wv = W1w + (size_t)o*512;
  float s = W1b[o];
  for (int k = 0; k < 512; k += 4){
    f32x4 a = *(const f32x4*)(ls + k);
    f32x4 w4 = *(const f32x4*)(wv + k);
    s = fmaf(a[0],w4[0], fmaf(a[1],w4[1], fmaf(a[2],w4[2], fmaf(a[3],w4[3], s))));
  }
  h0[b*256 + o] = s;
}

// ---------------- decoder: 32 blocks = batch, 1024 threads ----------------
// 4 barriers/step: gates -> B1 -> {dots(T<768, ring-8) ∥ scores(T>=768, LDS)}
//   -> B2 -> softmax -> B3 -> ctx(T<768, ring-4 on projt) -> B4.
// Depth-8/4 register rings keep ~8KB/wave of L2 loads in flight (the R3-R10
// decoders were latency-bound at ~2 in flight). Tail iterations preload next
// step's chunks (weights are step-invariant).
// n-gate: ctx projection (gcs) stays OUTSIDE the r* product (ref semantics).
#define DNR 160
__global__ __launch_bounds__(1024) void k_decoder(
  const unsigned short* __restrict__ Whd, const float* __restrict__ bhd,
  const float* __restrict__ gidx,            // [B][TD][768] f32 (includes bi_d)
  const unsigned short* __restrict__ encw2,  // [B*TE][256] bf16
  const float* __restrict__ encb2,           // [B*TE]
  const unsigned short* __restrict__ projt,  // [B][16][768][8] bf16
  const float* __restrict__ h0,
  unsigned short* __restrict__ outs_bf)      // [B][TD][256] bf16
{
  extern __shared__ char smem[];
  unsigned short* le = (unsigned short*)smem;            // 65536
  unsigned short* lw = (unsigned short*)(smem + 65536);  // DNR*512 = 81920
  float* h   = (float*)(smem + 147456);                  // 1024
  float* par = (float*)(smem + 148480);                  // 3072
  float* gcs = (float*)(smem + 151552);                  // 3072
  float* p   = (float*)(smem + 154624);                  // 512
  float* ebl = (float*)(smem + 155136);                  // 512  -> total 155648
  const int b = blockIdx.x, T = threadIdx.x;
  const unsigned short* ptc = projt + (size_t)b*98304;
  // ring sources (thread-invariant across steps)
  const unsigned short* wsrc = Whd + (size_t)T*8;        // + q*6144 (rows DNR..767)
  const unsigned short* csrc = ptc + (size_t)T*8;        // + q*6144 (ctx row T)
  uint4v wb[8], cb[4];
  const bool strm = (T >= DNR) && (T < 768);
  if (strm){
    #pragma unroll
    for (int d = 0; d < 8; ++d) wb[d] = *(const uint4v*)(wsrc + (size_t)d*6144);
  }
  if (T < 768){
    #pragma unroll
    for (int d = 0; d < 4; ++d) cb[d] = *(const uint4v*)(csrc + (size_t)d*6144);
  }
  // stage encw2[b] (rows XOR-swizzled by k-chunk)
  for (int cc = T; cc < 128*32; cc += 1024){
    int r = cc >> 5, q = cc & 31;
    *(uint4v*)&le[(r*32 + (q ^ (r & 31)))*8] =
        *(const uint4v*)(encw2 + ((size_t)(b*TEe + r) << 8) + (q << 3));
  }
  // stage Whd rows [0,DNR)
  for (int cc = T; cc < DNR*32; cc += 1024){
    int r = cc >> 5, q = cc & 31;
    *(uint4v*)&lw[(r*32 + (q ^ (r & 31)))*8] =
        *(const uint4v*)(Whd + (size_t)q*6144 + r*8);
  }
  for (int i = T; i < 256; i += 1024) h[i] = h0[b*256 + i];
  for (int i = T; i < 768; i += 1024) gcs[i] = 0.f;      // ctx_init = 0
  if (T < TEe) ebl[T] = encb2[b*TEe + T];
  float bh0 = 0.f, bh1 = 0.f, bh2 = 0.f;
  if (T < 256){ bh0 = bhd[T]; bh1 = bhd[T+256]; bh2 = bhd[T+512]; }
  __syncthreads();
  // prologue: dots on h0 + gi regs for t=0
  float g0 = 0.f, g1 = 0.f, g2 = 0.f;
  if (T < 256){
    const float* grow = gidx + (size_t)(b*TDd)*768;
    g0 = grow[T]; g1 = grow[T+256]; g2 = grow[T+512];
  }
  if (T < 768){
    float acc = 0.f;
    if (T < DNR){
      const unsigned short* lwr = lw + T*256;
      #pragma unroll
      for (int q = 0; q < 32; ++q){
        float hr[8];
        *(f32x4*)&hr[0] = *(const f32x4*)&h[q*8];
        *(f32x4*)&hr[4] = *(const f32x4*)&h[q*8+4];
        acc += dot8(*(const uint4v*)(lwr + ((q ^ (T & 31)) << 3)), hr);
      }
    } else {
      #pragma unroll
      for (int q = 0; q < 32; ++q){
        float hr[8];
        *(f32x4*)&hr[0] = *(const f32x4*)&h[q*8];
        *(f32x4*)&hr[4] = *(const f32x4*)&h[q*8+4];
        acc += dot8(wb[q & 7], hr);
        wb[q & 7] = *(const uint4v*)(wsrc + (size_t)((q < 24) ? (q + 8) : (q - 24))*6144);
      }
    }
    par[T] = acc;
  }
  __syncthreads();
  for (int t = 0; t < TDd; ++t){
    // gates: h_t from dots(par), ctx(gcs), gi(g-regs)
    if (T < 256){
      const float A0 = par[T] + bh0;
      const float A1 = par[T+256] + bh1;
      const float A2 = par[T+512] + bh2;
      const float r = sigmoidf_(g0 + gcs[T] + A0);
      const float z = sigmoidf_(g1 + gcs[T+256] + A1);
      const float n = tanhf(g2 + gcs[T+512] + r*A2);
      const float hnew = (1.f - z)*n + z*h[T];
      h[T] = hnew;
      outs_bf[(size_t)(b*TDd + t)*256 + T] = f2bf(hnew);
    }
    if (t + 1 == TDd) break;
    __syncthreads();                   // B1: h_t visible
    // P1: dots (T<768, ring) + gi prefetch (T<256) ∥ scores (T>=768, LDS encw2)
    if (T < 768){
      if (T < 256){
        const float* grow = gidx + (size_t)(b*TDd + t + 1)*768;
        g0 = grow[T]; g1 = grow[T+256]; g2 = grow[T+512];
      }
      float acc = 0.f;
      if (T < DNR){
        const unsigned short* lwr = lw + T*256;
        #pragma unroll
        for (int q = 0; q < 32; ++q){
          float hr[8];
          *(f32x4*)&hr[0] = *(const f32x4*)&h[q*8];
          *(f32x4*)&hr[4] = *(const f32x4*)&h[q*8+4];
          acc += dot8(*(const uint4v*)(lwr + ((q ^ (T & 31)) << 3)), hr);
        }
      } else {
        #pragma unroll
        for (int q = 0; q < 32; ++q){
          float hr[8];
          *(f32x4*)&hr[0] = *(const f32x4*)&h[q*8];
          *(f32x4*)&hr[4] = *(const f32x4*)&h[q*8+4];
          acc += dot8(wb[q & 7], hr);
          wb[q & 7] = *(const uint4v*)(wsrc + (size_t)((q < 24) ? (q + 8) : (q - 24))*6144);
        }
      }
      par[T] = acc;
    } else {
      const int i = T - 768, pos = i >> 1, kh = i & 1;
      const unsigned short* er = le + pos*256;
      float s = 0.f;
      #pragma unroll
      for (int ii = 0; ii < 16; ++ii){
        const int q = kh*16 + ii;
        float hr[8];
        *(f32x4*)&hr[0] = *(const f32x4*)&h[q*8];
        *(f32x4*)&hr[4] = *(const f32x4*)&h[q*8+4];
        s += dot8(*(const uint4v*)(er + ((q ^ (pos & 31)) << 3)), hr);
      }
      s += __shfl_xor(s, 1);
      if (kh == 0) p[pos] = s + ebl[pos];
    }
    __syncthreads();                   // B2: raw scores ready
    if (T < 64){
      float m = fmaxf(p[T], p[T+64]);
      for (int off = 32; off; off >>= 1) m = fmaxf(m, __shfl_xor(m, off));
      float e0 = __expf(p[T] - m), e1 = __expf(p[T+64] - m);
      float ss = e0 + e1;
      for (int off = 32; off; off >>= 1) ss += __shfl_xor(ss, off);
      float inv = 1.f / ss;
      p[T] = e0*inv; p[T+64] = e1*inv;
    }
    __syncthreads();                   // B3: softmax done
    // P3: ctx projection, row T over 128 enc positions (ring-4 on projt)
    if (T < 768){
      float c = 0.f;
      #pragma unroll
      for (int q = 0; q < 16; ++q){
        float pr[8];
        *(f32x4*)&pr[0] = *(const f32x4*)&p[q*8];
        *(f32x4*)&pr[4] = *(const f32x4*)&p[q*8+4];
        c += dot8(cb[q & 3], pr);
        cb[q & 3] = *(const uint4v*)(csrc + (size_t)((q < 12) ? (q + 4) : (q - 12))*6144);
      }
      gcs[T] = c;
    }
    __syncthreads();                   // B4: gcs ready for next gates
  }
}

extern "C" void kernel_launch(void* const* d_in, const int* in_sizes, int n_in,
                              void* d_out, int out_size, void* d_ws, size_t ws_size,
                              hipStream_t stream)
{
  (void)in_sizes; (void)n_in; (void)out_size;
  const int*   enc_in = (const int*)d_in[0];
  const int*   dec_in = (const int*)d_in[1];
  const float* embW   = (const float*)d_in[2];
  const float* Wi_f   = (const float*)d_in[3];
  const float* Wh_f   = (const float*)d_in[4];
  const float* bi_f   = (const float*)d_in[5];
  const float* bh_f   = (const float*)d_in[6];
  const float* Wi_b   = (const float*)d_in[7];
  const float* Wh_b   = (const float*)d_in[8];
  const float* bi_b   = (const float*)d_in[9];
  const float* bh_b   = (const float*)d_in[10];
  const float* Wi_d   = (const float*)d_in[11];
  const float* Wh_d   = (const float*)d_in[12];
  const float* bi_d   = (const float*)d_in[13];
  const float* bh_d   = (const float*)d_in[14];
  const float* W1_w   = (const float*)d_in[15];
  const float* W1_b   = (const float*)d_in[16];
  const float* W2_w   = (const float*)d_in[17];
  const float* W2_b   = (const float*)d_in[18];
  const float* lin_w  = (const float*)d_in[19];
  const float* lin_b  = (const float*)d_in[20];

  char* scr = (char*)d_out;
  float* emb_enc = (float*)(scr + 0);
  float* emb_dec = (float*)(scr + 4194304);
  float* gi_f    = (float*)(scr + 6291456);
  float* gi_b    = (float*)(scr + 18874368);
  float* gi_dx   = (float*)(scr + 31457280);
  float* enc     = (float*)(scr + 37748736);
  float* projf   = (float*)(scr + 46137344);
  unsigned short* whf_bf = (unsigned short*)(scr + 58720256);
  unsigned short* whb_bf = (unsigned short*)(scr + 59113472);
  unsigned short* whd_bf = (unsigned short*)(scr + 59506688);
  unsigned short* encw2  = (unsigned short*)(scr + 59899904);
  unsigned short* projt  = (unsigned short*)(scr + 61997056);
  float* encb2 = (float*)(scr + 68288512);
  int*   sizes = (int*)(scr + 68304896);
  float* h0    = (float*)(scr + 68305024);

  unsigned short* outs_bf = (unsigned short*)d_ws;
  unsigned short* lin_bf  = (unsigned short*)((char*)d_ws + (1<<20));
  const bool big = ws_size >= (size_t)(1<<20) + 16384000u + 1024u;

  // allow >64KB dynamic LDS (capture-safe host attribute; idempotent)
  hipFuncSetAttribute((const void*)k_encoder, hipFuncAttributeMaxDynamicSharedMemorySize, 141312);
  hipFuncSetAttribute((const void*)k_decoder, hipFuncAttributeMaxDynamicSharedMemorySize, 155648);

  k_sizes<<<1, 32, 0, stream>>>(enc_in, sizes);
  k_gather<<<Bb*TEe, 256, 0, stream>>>(enc_in, embW, emb_enc, Bb*TEe);
  k_gather<<<Bb*TDd, 256, 0, stream>>>(dec_in, embW, emb_dec, Bb*TDd);
  k_chunkw<<<768, 256, 0, stream>>>(Wh_f, whf_bf, 768);
  k_chunkw<<<768, 256, 0, stream>>>(Wh_b, whb_bf, 768);
  k_chunkw<<<768, 256, 0, stream>>>(Wh_d, whd_bf, 768);
  if (big) k_extract_bf16<<<32000, 256, 0, stream>>>(lin_w, lin_bf, 32000*256);

  k_gemm<false,false,false,false><<<dim3(6,32), 256, 0, stream>>>(
      emb_enc, Wi_f, bi_f, gi_f, 4096, 768, 256, 256, 256, 768);
  k_gemm<false,false,false,false><<<dim3(6,32), 256, 0, stream>>>(
      emb_enc, Wi_b, bi_b, gi_b, 4096, 768, 256, 256, 256, 768);
  k_gemm<false,false,false,false><<<dim3(6,16), 256, 0, stream>>>(
      emb_dec, Wi_d + 512, bi_d, gi_dx, 2048, 768, 256, 256, 768, 768);

  k_encoder<<<64, 1024, 141312, stream>>>(whf_bf, whb_bf, bh_f, bh_b, gi_f, gi_b, enc);
  k_encb2<<<Bb*TEe, 64, 0, stream>>>(enc, W2_b, encb2);

  k_gemm<false,false,true,true><<<dim3(2,32), 256, 0, stream>>>(
      enc, W2_w, nullptr, encw2, 4096, 256, 512, 512, 256, 256);
  k_gemm<false,false,false,false><<<dim3(6,32), 256, 0, stream>>>(
      enc, Wi_d, nullptr, projf, 4096, 768, 512, 512, 768, 768);
  k_projchunk<<<(Bb*16*768*8)/256, 256, 0, stream>>>(projf, projt);
  k_hinit<<<Bb, 256, 0, stream>>>(enc, sizes, W1_w, W1_b, h0);

  k_decoder<<<Bb, 1024, 155648, stream>>>(whd_bf, bh_d, gi_dx, encw2, encb2, projt, h0, outs_bf);

  if (big)
    k_gemm<true,true,false,false><<<dim3(250,16), 256, 0, stream>>>(
        outs_bf, lin_bf, lin_b, d_out, 2048, 32000, 256, 256, 256, 32000);
  else
    k_gemm<true,false,false,false><<<dim3(250,16), 256, 0, stream>>>(
        outs_bf, lin_w, lin_b, d_out, 2048, 32000, 256, 256, 256, 32000);
}

// Round 12
// 1993.939 us; speedup vs baseline: 1.9741x; 1.0112x over previous
//
#include <hip/hip_runtime.h>
#include <hip/hip_bf16.h>

#define Vv 32000
#define Ee 256
#define Hh 256
#define Bb 32
#define TEe 128
#define TDd 64

typedef __attribute__((ext_vector_type(4))) float f32x4;
typedef __attribute__((ext_vector_type(8))) short short8;
typedef __attribute__((ext_vector_type(2))) unsigned int uint2v;
typedef __attribute__((ext_vector_type(4))) unsigned int uint4v;

static __device__ __forceinline__ unsigned short f2bf(float f){
  unsigned u = __float_as_uint(f);
  u += 0x7fffu + ((u >> 16) & 1u);           // round-to-nearest-even
  return (unsigned short)(u >> 16);
}
static __device__ __forceinline__ unsigned pack2(float a, float b){
  return ((unsigned)f2bf(b) << 16) | (unsigned)f2bf(a);
}
// dot of 8 packed bf16 (uint4) with 8 f32
static __device__ __forceinline__ float dot8(uint4v u, const float* hh){
  float s = 0.f;
  #pragma unroll
  for (int i = 0; i < 4; ++i){
    unsigned w = u[i];
    s = fmaf(__uint_as_float(w << 16),        hh[2*i],   s);
    s = fmaf(__uint_as_float(w & 0xffff0000u), hh[2*i+1], s);
  }
  return s;
}
static __device__ __forceinline__ float sigmoidf_(float x){
  return 1.f / (1.f + __expf(-x));
}

// ---------------- small prep kernels ----------------
__global__ void k_sizes(const int* __restrict__ enc_in, int* __restrict__ sizes){
  int b = threadIdx.x;
  if (b < Bb){
    int c = 0;
    for (int t = 0; t < TEe; ++t) c += (enc_in[b*TEe + t] > 0);
    sizes[b] = c;
  }
}

__global__ void k_gather(const int* __restrict__ tok, const float* __restrict__ embW,
                         float* __restrict__ out, int rows){
  int i = blockIdx.x * 256 + threadIdx.x;
  int r = i >> 8, c = i & 255;
  if (r < rows) out[i] = embW[(size_t)tok[r]*Ee + c];
}

// f32 -> bf16 row-major
__global__ void k_extract_bf16(const float* __restrict__ src, unsigned short* __restrict__ dst,
                               int n){
  int i = blockIdx.x * 256 + threadIdx.x;
  if (i < n) dst[i] = f2bf(src[i]);
}

// f32 [rows][256] -> chunked bf16 [32][rows][8]  (kb-major for coalesced staging)
__global__ void k_chunkw(const float* __restrict__ src, unsigned short* __restrict__ dst, int rows){
  int idx = blockIdx.x * 256 + threadIdx.x;
  if (idx < rows * 256){
    int i = idx & 7, r = (idx >> 3) % rows, kb = idx / (rows * 8);
    dst[idx] = f2bf(src[(size_t)r*256 + kb*8 + i]);
  }
}

// projf f32 [B*TE][768] -> chunked bf16 [B][16][768][8]
__global__ void k_projchunk(const float* __restrict__ in, unsigned short* __restrict__ out){
  int idx = blockIdx.x * 256 + threadIdx.x;     // total B*16*768*8
  int i = idx & 7;
  int t1 = idx >> 3;
  int n = t1 % 768;
  int t2 = t1 / 768;
  int kb = t2 & 15, b = t2 >> 4;
  out[idx] = f2bf(in[(size_t)(b*TEe + kb*8 + i)*768 + n]);
}

// ---------------- bf16 MFMA GEMM: C[M,N] = A[M,K] * B^T + bias ----------------
template<bool A_BF16, bool B_BF16, bool B_KMAJOR, bool OUT_BF16>
__global__ __launch_bounds__(256) void k_gemm(
  const void* __restrict__ Av, const void* __restrict__ Bv,
  const float* __restrict__ bias, void* __restrict__ Cv,
  int M, int N, int K, int lda, int ldb, int ldc)
{
  __shared__ unsigned short lA[128*40];
  __shared__ unsigned short lB[128*40];
  const int tid  = threadIdx.x;
  const int lane = tid & 63;
  const int w = tid >> 6, wr = w >> 1, wc = w & 1;
  const int m0 = blockIdx.y * 128, n0 = blockIdx.x * 128;
  f32x4 acc[4][4];
  #pragma unroll
  for (int i = 0; i < 4; ++i)
    #pragma unroll
    for (int j = 0; j < 4; ++j) acc[i][j] = (f32x4){0.f,0.f,0.f,0.f};

  for (int k0 = 0; k0 < K; k0 += 32){
    if (A_BF16){
      const unsigned short* A = (const unsigned short*)Av;
      #pragma unroll
      for (int it = 0; it < 2; ++it){
        int idx = tid + it*256; int r = idx >> 2, q = idx & 3;
        *(uint4v*)&lA[r*40 + q*8] = *(const uint4v*)(A + (size_t)(m0+r)*lda + k0 + q*8);
      }
    } else {
      const float* A = (const float*)Av;
      #pragma unroll
      for (int it = 0; it < 4; ++it){
        int idx = tid + it*256; int r = idx >> 3, q = idx & 7;
        f32x4 v = *(const f32x4*)(A + (size_t)(m0+r)*lda + k0 + q*4);
        uint2v pk; pk[0] = pack2(v[0], v[1]); pk[1] = pack2(v[2], v[3]);
        *(uint2v*)&lA[r*40 + q*4] = pk;
      }
    }
    if (B_KMAJOR){
      const float* Bp = (const float*)Bv;
      #pragma unroll
      for (int it = 0; it < 4; ++it){
        int idx = tid + it*256; int kk = idx >> 5, nq = idx & 31;
        f32x4 v = *(const f32x4*)(Bp + (size_t)(k0+kk)*ldb + n0 + nq*4);
        #pragma unroll
        for (int s2 = 0; s2 < 4; ++s2) lB[(nq*4+s2)*40 + kk] = f2bf(v[s2]);
      }
    } else if (B_BF16){
      const unsigned short* Bp = (const unsigned short*)Bv;
      #pragma unroll
      for (int it = 0; it < 2; ++it){
        int idx = tid + it*256; int r = idx >> 2, q = idx & 3;
        *(uint4v*)&lB[r*40 + q*8] = *(const uint4v*)(Bp + (size_t)(n0+r)*ldb + k0 + q*8);
      }
    } else {
      const float* Bp = (const float*)Bv;
      #pragma unroll
      for (int it = 0; it < 4; ++it){
        int idx = tid + it*256; int r = idx >> 3, q = idx & 7;
        f32x4 v = *(const f32x4*)(Bp + (size_t)(n0+r)*ldb + k0 + q*4);
        uint2v pk; pk[0] = pack2(v[0], v[1]); pk[1] = pack2(v[2], v[3]);
        *(uint2v*)&lB[r*40 + q*4] = pk;
      }
    }
    __syncthreads();
    short8 av[4], bv[4];
    #pragma unroll
    for (int i = 0; i < 4; ++i)
      av[i] = *(const short8*)&lA[(wr*64 + i*16 + (lane&15))*40 + (lane>>4)*8];
    #pragma unroll
    for (int j = 0; j < 4; ++j)
      bv[j] = *(const short8*)&lB[(wc*64 + j*16 + (lane&15))*40 + (lane>>4)*8];
    #pragma unroll
    for (int i = 0; i < 4; ++i)
      #pragma unroll
      for (int j = 0; j < 4; ++j)
        acc[i][j] = __builtin_amdgcn_mfma_f32_16x16x32_bf16(av[i], bv[j], acc[i][j], 0, 0, 0);
    __syncthreads();
  }
  #pragma unroll
  for (int i = 0; i < 4; ++i){
    #pragma unroll
    for (int j = 0; j < 4; ++j){
      int col = n0 + wc*64 + j*16 + (lane & 15);
      float bb = bias ? bias[col] : 0.f;
      #pragma unroll
      for (int r = 0; r < 4; ++r){
        int row = m0 + wr*64 + i*16 + (lane>>4)*4 + r;
        float v = acc[i][j][r] + bb;
        if (OUT_BF16) ((unsigned short*)Cv)[(size_t)row*ldc + col] = f2bf(v);
        else          ((float*)Cv)[(size_t)row*ldc + col] = v;
      }
    }
  }
}

// ---------------- encoder: 64 blocks = (dir, batch), 512 threads ----------------
// 512-thread blocks get a 128-VGPR cap (measured R5/R6) so the depth-8 ring
// (32 VGPR) actually lives in registers (1024-thr blocks were capped at 64 and
// the R11 rings were rematerialized). Rows 0-255 in LDS (2 thr/row); row 256+T
// streamed full-row with the ring; tail of each step's ring preloads next
// step's chunks 0-7 (weights are step-invariant).
__global__ __launch_bounds__(512, 1) void k_encoder(
  const unsigned short* __restrict__ Whf, const unsigned short* __restrict__ Whb,
  const float* __restrict__ bhf, const float* __restrict__ bhb,
  const float* __restrict__ gif, const float* __restrict__ gib,
  float* __restrict__ encoded)
{
  extern __shared__ char smem[];
  unsigned short* lw = (unsigned short*)smem;        // 131072
  float* hA   = (float*)(smem + 131072);             // 1024
  float* hB   = (float*)(smem + 132096);             // 1024
  float* parL = (float*)(smem + 133120);             // 512*4 = 2048
  float* parS = (float*)(smem + 135168);             // 512*4 = 2048 -> 137216
  const int dir = blockIdx.x & 1, b = blockIdx.x >> 1;
  const unsigned short* Wh = dir ? Whb : Whf;
  const float* bh = dir ? bhb : bhf;
  const float* gi = dir ? gib : gif;
  const int T = threadIdx.x;                         // [0,512)
  const int rL = T >> 1, hfq = (T & 1)*16;           // LDS part: row rL, chunks hfq..hfq+15
  const unsigned short* wsrc = Wh + (size_t)(256 + T)*8;   // stream row 256+T, +q*6144
  uint4v wb[8];
  #pragma unroll
  for (int d = 0; d < 8; ++d) wb[d] = *(const uint4v*)(wsrc + (size_t)d*6144);
  for (int cc = T; cc < 256*32; cc += 512){
    int r = cc >> 5, q = cc & 31;
    *(uint4v*)&lw[(r*32 + (q ^ (r & 31)))*8] = *(const uint4v*)(Wh + (size_t)q*6144 + r*8);
  }
  float bh0 = 0.f, bh1 = 0.f, bh2 = 0.f;
  if (T < 256){ bh0 = bh[T]; bh1 = bh[T+256]; bh2 = bh[T+512]; hA[T] = 0.f; }
  __syncthreads();
  const float* hc = hA; float* hn = hB;
  for (int s = 0; s < TEe; ++s){
    const int t = dir ? (TEe-1-s) : s;
    // LDS part: 16 chunks of row rL
    {
      const unsigned short* lwr = lw + rL*256;
      float a = 0.f;
      #pragma unroll
      for (int i = 0; i < 16; ++i){
        const int q = hfq + i;
        float hr[8];
        *(f32x4*)&hr[0] = *(const f32x4*)&hc[q*8];
        *(f32x4*)&hr[4] = *(const f32x4*)&hc[q*8+4];
        a += dot8(*(const uint4v*)(lwr + ((q ^ (rL & 31)) << 3)), hr);
      }
      parL[(T & 1)*256 + rL] = a;
    }
    // stream part: full row 256+T, depth-8 ring
    {
      float a = 0.f;
      #pragma unroll
      for (int q = 0; q < 32; ++q){
        float hr[8];
        *(f32x4*)&hr[0] = *(const f32x4*)&hc[q*8];
        *(f32x4*)&hr[4] = *(const f32x4*)&hc[q*8+4];
        a += dot8(wb[q & 7], hr);
        wb[q & 7] = *(const uint4v*)(wsrc + (size_t)((q < 24) ? (q + 8) : (q - 24))*6144);
      }
      parS[T] = a;
    }
    __syncthreads();                   // B1: partials ready
    if (T < 256){
      const int j = T;
      const float* grow = gi + (size_t)(b*TEe + t)*768;
      const float A0 = parL[j] + parL[256+j] + bh0;
      const float A1 = parS[j] + bh1;
      const float A2 = parS[256+j] + bh2;
      const float r = sigmoidf_(grow[j] + A0);
      const float z = sigmoidf_(grow[j+256] + A1);
      const float n = tanhf(grow[j+512] + r*A2);
      const float hnew = (1.f - z)*n + z*hc[j];
      hn[j] = hnew;
      encoded[(size_t)(b*TEe + t)*512 + dir*256 + j] = hnew;
    }
    __syncthreads();                   // B2: h_new visible
    const float* tmp = hc; hc = hn; hn = (float*)tmp;
  }
}

// encb2[r] = encoded[r,:512] . W2_b
__global__ void k_encb2(const float* __restrict__ encoded, const float* __restrict__ W2b,
                        float* __restrict__ encb2){
  int r = blockIdx.x, l = threadIdx.x;
  const float* e = encoded + (size_t)r*512;
  float s = 0.f;
  for (int k = l; k < 512; k += 64) s += e[k]*W2b[k];
  for (int off = 32; off; off >>= 1) s += __shfl_down(s, off);
  if (l == 0) encb2[r] = s;
}

__global__ void k_hinit(const float* __restrict__ encoded, const int* __restrict__ sizes,
                        const float* __restrict__ W1w, const float* __restrict__ W1b,
                        float* __restrict__ h0){
  int b = blockIdx.x, o = threadIdx.x;
  int idx = sizes[b] - 1;
  idx = idx < 0 ? 0 : (idx > TEe-1 ? TEe-1 : idx);
  const float* ls = encoded + (size_t)(b*TEe + idx)*512;
  const float* wv = W1w + (size_t)o*512;
  float s = W1b[o];
  for (int k = 0; k < 512; k += 4){
    f32x4 a = *(const f32x4*)(ls + k);
    f32x4 w4 = *(const f32x4*)(wv + k);
    s = fmaf(a[0],w4[0], fmaf(a[1],w4[1], fmaf(a[2],w4[2], fmaf(a[3],w4[3], s))));
  }
  h0[b*256 + o] = s;
}

// ---------------- decoder: 32 blocks = batch, 512 threads ----------------
// 4 barriers/step: gates -> B1 -> {dots(LDS rows 0-127 + ring-8 rows 128-639 +
// ring-2 rows 640-767) + scores(LDS encw2)} -> B2 -> softmax -> B3 ->
// ctx(ring-4 rows 0-511 + ring-2 rows 512-767) -> B4.
// 512 threads -> 128-VGPR cap -> rings persist in registers (R11's 1024-thr
// version was capped at 64 and remat'd). Rings preload next step's chunks at
// the tail. n-gate: ctx (gc) stays OUTSIDE the r* product (ref semantics);
// bh_n stays INSIDE (r * (Wh_n.h + bh_n)).
#define DLR 128
__global__ __launch_bounds__(512, 1) void k_decoder(
  const unsigned short* __restrict__ Whd, const float* __restrict__ bhd,
  const float* __restrict__ gidx,            // [B][TD][768] f32 (includes bi_d)
  const unsigned short* __restrict__ encw2,  // [B*TE][256] bf16
  const float* __restrict__ encb2,           // [B*TE]
  const unsigned short* __restrict__ projt,  // [B][16][768][8] bf16
  const float* __restrict__ h0,
  unsigned short* __restrict__ outs_bf)      // [B][TD][256] bf16
{
  extern __shared__ char smem[];
  unsigned short* le = (unsigned short*)smem;            // 65536
  unsigned short* lw = (unsigned short*)(smem + 65536);  // DLR*512 = 65536
  float* h    = (float*)(smem + 131072);                 // 1024
  float* parL = (float*)(smem + 132096);                 // 2048 (4 quarters x 128)
  float* parS1= (float*)(smem + 134144);                 // 2048 (rows 128-639)
  float* parS2= (float*)(smem + 136192);                 // 2048 (4 quarters x 128, rows 640-767)
  float* gcs  = (float*)(smem + 138240);                 // 2048 (ctx rows 0-511)
  float* cpar = (float*)(smem + 140288);                 // 2048 (2 halves x 256, ctx rows 512-767)
  float* p    = (float*)(smem + 142336);                 // 512
  float* ebl  = (float*)(smem + 142848);                 // 512 -> total 143360
  const int b = blockIdx.x, T = threadIdx.x;             // [0,512)
  const unsigned short* ptc = projt + (size_t)b*98304;
  // per-thread stream sources (step-invariant)
  const unsigned short* wsrcM = Whd + (size_t)(DLR + T)*8;     // rows 128..639
  const int trow = 640 + (T >> 2), tq = (T & 3)*8;             // rows 640..767
  const unsigned short* wsrcT = Whd + (size_t)trow*8;
  const unsigned short* csrcM = ptc + (size_t)T*8;             // ctx rows 0..511
  const int crow = 512 + (T >> 1), cq = (T & 1)*8;             // ctx rows 512..767
  const unsigned short* csrcT = ptc + (size_t)crow*8;
  uint4v wb[8], wb2[2], cb[4], cb2[2];
  #pragma unroll
  for (int d = 0; d < 8; ++d) wb[d] = *(const uint4v*)(wsrcM + (size_t)d*6144);
  wb2[0] = *(const uint4v*)(wsrcT + (size_t)tq*6144);
  wb2[1] = *(const uint4v*)(wsrcT + (size_t)(tq+1)*6144);
  #pragma unroll
  for (int d = 0; d < 4; ++d) cb[d] = *(const uint4v*)(csrcM + (size_t)d*6144);
  cb2[0] = *(const uint4v*)(csrcT + (size_t)cq*6144);
  cb2[1] = *(const uint4v*)(csrcT + (size_t)(cq+1)*6144);
  // stage encw2[b] (rows XOR-swizzled by k-chunk)
  for (int cc = T; cc < 128*32; cc += 512){
    int r = cc >> 5, q = cc & 31;
    *(uint4v*)&le[(r*32 + (q ^ (r & 31)))*8] =
        *(const uint4v*)(encw2 + ((size_t)(b*TEe + r) << 8) + (q << 3));
  }
  // stage Whd rows [0,DLR)
  for (int cc = T; cc < DLR*32; cc += 512){
    int r = cc >> 5, q = cc & 31;
    *(uint4v*)&lw[(r*32 + (q ^ (r & 31)))*8] =
        *(const uint4v*)(Whd + (size_t)q*6144 + r*8);
  }
  for (int i = T; i < 256; i += 512) h[i] = h0[b*256 + i];
  gcs[T] = 0.f; cpar[T] = 0.f;                           // ctx_init = 0
  if (T < TEe) ebl[T] = encb2[b*TEe + T];
  float bh0 = 0.f, bh1 = 0.f, bh2 = 0.f;
  if (T < 256){ bh0 = bhd[T]; bh1 = bhd[T+256]; bh2 = bhd[T+512]; }
  __syncthreads();
  // prologue: gi for t=0 + dots on h0
  float g0 = 0.f, g1 = 0.f, g2 = 0.f;
  if (T < 256){
    const float* grow = gidx + (size_t)(b*TDd)*768;
    g0 = grow[T]; g1 = grow[T+256]; g2 = grow[T+512];
  }
  #define DOTS_BODY                                                            \
  {                                                                            \
    { const int rL2 = T >> 2, qb = (T & 3)*8;                                  \
      const unsigned short* lwr = lw + rL2*256;                                \
      float a = 0.f;                                                           \
      _Pragma("unroll")                                                        \
      for (int i = 0; i < 8; ++i){                                             \
        const int q = qb + i;                                                  \
        float hr[8];                                                           \
        *(f32x4*)&hr[0] = *(const f32x4*)&h[q*8];                              \
        *(f32x4*)&hr[4] = *(const f32x4*)&h[q*8+4];                            \
        a += dot8(*(const uint4v*)(lwr + ((q ^ (rL2 & 31)) << 3)), hr);        \
      }                                                                        \
      parL[(T & 3)*128 + rL2] = a;                                             \
    }                                                                          \
    { float a = 0.f;                                                           \
      _Pragma("unroll")                                                        \
      for (int q = 0; q < 32; ++q){                                            \
        float hr[8];                                                           \
        *(f32x4*)&hr[0] = *(const f32x4*)&h[q*8];                              \
        *(f32x4*)&hr[4] = *(const f32x4*)&h[q*8+4];                            \
        a += dot8(wb[q & 7], hr);                                              \
        wb[q & 7] = *(const uint4v*)(wsrcM + (size_t)((q < 24) ? (q + 8) : (q - 24))*6144); \
      }                                                                        \
      parS1[T] = a;                                                            \
    }                                                                          \
    { float a = 0.f;                                                           \
      _Pragma("unroll")                                                        \
      for (int i = 0; i < 8; ++i){                                             \
        const int q = tq + i;                                                  \
        float hr[8];                                                           \
        *(f32x4*)&hr[0] = *(const f32x4*)&h[q*8];                              \
        *(f32x4*)&hr[4] = *(const f32x4*)&h[q*8+4];                            \
        a += dot8(wb2[i & 1], hr);                                             \
        wb2[i & 1] = *(const uint4v*)(wsrcT + (size_t)(tq + ((i < 6) ? (i + 2) : (i - 6)))*6144); \
      }                                                                        \
      parS2[(T & 3)*128 + (T >> 2)] = a;                                       \
    }                                                                          \
  }
  DOTS_BODY
  __syncthreads();
  for (int t = 0; t < TDd; ++t){
    // gates (T<256): par/gcs/cpar from previous phase, gi in regs
    if (T < 256){
      const int j = T;
      float A0, A2;
      if (j < 128){
        A0 = parL[j] + parL[128+j] + parL[256+j] + parL[384+j];
        A2 = parS1[384+j];
      } else {
        A0 = parS1[j-128];
        A2 = parS2[j-128] + parS2[j] + parS2[j+128] + parS2[j+256];
      }
      const float A1 = parS1[128+j];
      const float gcr = gcs[j];
      const float gcz = gcs[256+j];
      const float gcn = cpar[j] + cpar[256+j];
      const float r = sigmoidf_(g0 + gcr + A0 + bh0);
      const float z = sigmoidf_(g1 + gcz + A1 + bh1);
      const float n = tanhf(g2 + gcn + r*(A2 + bh2));
      const float hnew = (1.f - z)*n + z*h[j];
      h[j] = hnew;
      outs_bf[(size_t)(b*TDd + t)*256 + j] = f2bf(hnew);
    }
    if (t + 1 == TDd) break;
    __syncthreads();                   // B1: h_t visible
    // P1: dots (rings) + gi prefetch + scores (LDS encw2)
    if (T < 256){
      const float* grow = gidx + (size_t)(b*TDd + t + 1)*768;
      g0 = grow[T]; g1 = grow[T+256]; g2 = grow[T+512];
    }
    DOTS_BODY
    {
      const int pos = T >> 2, kq = (T & 3)*8;
      const unsigned short* er = le + pos*256;
      float s = 0.f;
      #pragma unroll
      for (int i = 0; i < 8; ++i){
        const int q = kq + i;
        float hr[8];
        *(f32x4*)&hr[0] = *(const f32x4*)&h[q*8];
        *(f32x4*)&hr[4] = *(const f32x4*)&h[q*8+4];
        s += dot8(*(const uint4v*)(er + ((q ^ (pos & 31)) << 3)), hr);
      }
      s += __shfl_xor(s, 1);
      s += __shfl_xor(s, 2);
      if ((T & 3) == 0) p[pos] = s + ebl[pos];
    }
    __syncthreads();                   // B2: raw scores ready
    if (T < 64){
      float m = fmaxf(p[T], p[T+64]);
      for (int off = 32; off; off >>= 1) m = fmaxf(m, __shfl_xor(m, off));
      float e0 = __expf(p[T] - m), e1 = __expf(p[T+64] - m);
      float ss = e0 + e1;
      for (int off = 32; off; off >>= 1) ss += __shfl_xor(ss, off);
      float inv = 1.f / ss;
      p[T] = e0*inv; p[T+64] = e1*inv;
    }
    __syncthreads();                   // B3: softmax done
    // ctx: row T (ring-4) + half of row 512+(T>>1) (ring-2)
    {
      float c = 0.f;
      #pragma unroll
      for (int q = 0; q < 16; ++q){
        float pr[8];
        *(f32x4*)&pr[0] = *(const f32x4*)&p[q*8];
        *(f32x4*)&pr[4] = *(const f32x4*)&p[q*8+4];
        c += dot8(cb[q & 3], pr);
        cb[q & 3] = *(const uint4v*)(csrcM + (size_t)((q < 12) ? (q + 4) : (q - 12))*6144);
      }
      gcs[T] = c;
      float c2 = 0.f;
      #pragma unroll
      for (int i = 0; i < 8; ++i){
        const int q = cq + i;
        float pr[8];
        *(f32x4*)&pr[0] = *(const f32x4*)&p[q*8];
        *(f32x4*)&pr[4] = *(const f32x4*)&p[q*8+4];
        c2 += dot8(cb2[i & 1], pr);
        cb2[i & 1] = *(const uint4v*)(csrcT + (size_t)(cq + ((i < 6) ? (i + 2) : (i - 6)))*6144);
      }
      cpar[(T & 1)*256 + (T >> 1)] = c2;
    }
    __syncthreads();                   // B4: gcs/cpar ready for next gates
  }
  #undef DOTS_BODY
}

extern "C" void kernel_launch(void* const* d_in, const int* in_sizes, int n_in,
                              void* d_out, int out_size, void* d_ws, size_t ws_size,
                              hipStream_t stream)
{
  (void)in_sizes; (void)n_in; (void)out_size;
  const int*   enc_in = (const int*)d_in[0];
  const int*   dec_in = (const int*)d_in[1];
  const float* embW   = (const float*)d_in[2];
  const float* Wi_f   = (const float*)d_in[3];
  const float* Wh_f   = (const float*)d_in[4];
  const float* bi_f   = (const float*)d_in[5];
  const float* bh_f   = (const float*)d_in[6];
  const float* Wi_b   = (const float*)d_in[7];
  const float* Wh_b   = (const float*)d_in[8];
  const float* bi_b   = (const float*)d_in[9];
  const float* bh_b   = (const float*)d_in[10];
  const float* Wi_d   = (const float*)d_in[11];
  const float* Wh_d   = (const float*)d_in[12];
  const float* bi_d   = (const float*)d_in[13];
  const float* bh_d   = (const float*)d_in[14];
  const float* W1_w   = (const float*)d_in[15];
  const float* W1_b   = (const float*)d_in[16];
  const float* W2_w   = (const float*)d_in[17];
  const float* W2_b   = (const float*)d_in[18];
  const float* lin_w  = (const float*)d_in[19];
  const float* lin_b  = (const float*)d_in[20];

  char* scr = (char*)d_out;
  float* emb_enc = (float*)(scr + 0);
  float* emb_dec = (float*)(scr + 4194304);
  float* gi_f    = (float*)(scr + 6291456);
  float* gi_b    = (float*)(scr + 18874368);
  float* gi_dx   = (float*)(scr + 31457280);
  float* enc     = (float*)(scr + 37748736);
  float* projf   = (float*)(scr + 46137344);
  unsigned short* whf_bf = (unsigned short*)(scr + 58720256);
  unsigned short* whb_bf = (unsigned short*)(scr + 59113472);
  unsigned short* whd_bf = (unsigned short*)(scr + 59506688);
  unsigned short* encw2  = (unsigned short*)(scr + 59899904);
  unsigned short* projt  = (unsigned short*)(scr + 61997056);
  float* encb2 = (float*)(scr + 68288512);
  int*   sizes = (int*)(scr + 68304896);
  float* h0    = (float*)(scr + 68305024);

  unsigned short* outs_bf = (unsigned short*)d_ws;
  unsigned short* lin_bf  = (unsigned short*)((char*)d_ws + (1<<20));
  const bool big = ws_size >= (size_t)(1<<20) + 16384000u + 1024u;

  // allow >64KB dynamic LDS (capture-safe host attribute; idempotent)
  hipFuncSetAttribute((const void*)k_encoder, hipFuncAttributeMaxDynamicSharedMemorySize, 137216);
  hipFuncSetAttribute((const void*)k_decoder, hipFuncAttributeMaxDynamicSharedMemorySize, 143360);

  k_sizes<<<1, 32, 0, stream>>>(enc_in, sizes);
  k_gather<<<Bb*TEe, 256, 0, stream>>>(enc_in, embW, emb_enc, Bb*TEe);
  k_gather<<<Bb*TDd, 256, 0, stream>>>(dec_in, embW, emb_dec, Bb*TDd);
  k_chunkw<<<768, 256, 0, stream>>>(Wh_f, whf_bf, 768);
  k_chunkw<<<768, 256, 0, stream>>>(Wh_b, whb_bf, 768);
  k_chunkw<<<768, 256, 0, stream>>>(Wh_d, whd_bf, 768);
  if (big) k_extract_bf16<<<32000, 256, 0, stream>>>(lin_w, lin_bf, 32000*256);

  k_gemm<false,false,false,false><<<dim3(6,32), 256, 0, stream>>>(
      emb_enc, Wi_f, bi_f, gi_f, 4096, 768, 256, 256, 256, 768);
  k_gemm<false,false,false,false><<<dim3(6,32), 256, 0, stream>>>(
      emb_enc, Wi_b, bi_b, gi_b, 4096, 768, 256, 256, 256, 768);
  k_gemm<false,false,false,false><<<dim3(6,16), 256, 0, stream>>>(
      emb_dec, Wi_d + 512, bi_d, gi_dx, 2048, 768, 256, 256, 768, 768);

  k_encoder<<<64, 512, 137216, stream>>>(whf_bf, whb_bf, bh_f, bh_b, gi_f, gi_b, enc);
  k_encb2<<<Bb*TEe, 64, 0, stream>>>(enc, W2_b, encb2);

  k_gemm<false,false,true,true><<<dim3(2,32), 256, 0, stream>>>(
      enc, W2_w, nullptr, encw2, 4096, 256, 512, 512, 256, 256);
  k_gemm<false,false,false,false><<<dim3(6,32), 256, 0, stream>>>(
      enc, Wi_d, nullptr, projf, 4096, 768, 512, 512, 768, 768);
  k_projchunk<<<(Bb*16*768*8)/256, 256, 0, stream>>>(projf, projt);
  k_hinit<<<Bb, 256, 0, stream>>>(enc, sizes, W1_w, W1_b, h0);

  k_decoder<<<Bb, 512, 143360, stream>>>(whd_bf, bh_d, gi_dx, encw2, encb2, projt, h0, outs_bf);

  if (big)
    k_gemm<true,true,false,false><<<dim3(250,16), 256, 0, stream>>>(
        outs_bf, lin_bf, lin_b, d_out, 2048, 32000, 256, 256, 256, 32000);
  else
    k_gemm<true,false,false,false><<<dim3(250,16), 256, 0, stream>>>(
        outs_bf, lin_w, lin_b, d_out, 2048, 32000, 256, 256, 256, 32000);
}

// Round 13
// 1703.217 us; speedup vs baseline: 2.3110x; 1.1707x over previous
//
#include <hip/hip_runtime.h>
#include <hip/hip_bf16.h>

#define Vv 32000
#define Ee 256
#define Hh 256
#define Bb 32
#define TEe 128
#define TDd 64

typedef __attribute__((ext_vector_type(4))) float f32x4;
typedef __attribute__((ext_vector_type(8))) short short8;
typedef __attribute__((ext_vector_type(2))) unsigned int uint2v;
typedef __attribute__((ext_vector_type(4))) unsigned int uint4v;

static __device__ __forceinline__ unsigned short f2bf(float f){
  unsigned u = __float_as_uint(f);
  u += 0x7fffu + ((u >> 16) & 1u);           // round-to-nearest-even
  return (unsigned short)(u >> 16);
}
static __device__ __forceinline__ unsigned pack2(float a, float b){
  return ((unsigned)f2bf(b) << 16) | (unsigned)f2bf(a);
}
// dot of 8 packed bf16 (uint4) with 8 f32
static __device__ __forceinline__ float dot8(uint4v u, const float* hh){
  float s = 0.f;
  #pragma unroll
  for (int i = 0; i < 4; ++i){
    unsigned w = u[i];
    s = fmaf(__uint_as_float(w << 16),        hh[2*i],   s);
    s = fmaf(__uint_as_float(w & 0xffff0000u), hh[2*i+1], s);
  }
  return s;
}
static __device__ __forceinline__ float sigmoidf_(float x){
  return 1.f / (1.f + __expf(-x));
}

// ---------------- small prep kernels ----------------
__global__ void k_sizes(const int* __restrict__ enc_in, int* __restrict__ sizes){
  int b = threadIdx.x;
  if (b < Bb){
    int c = 0;
    for (int t = 0; t < TEe; ++t) c += (enc_in[b*TEe + t] > 0);
    sizes[b] = c;
  }
}

__global__ void k_gather(const int* __restrict__ tok, const float* __restrict__ embW,
                         float* __restrict__ out, int rows){
  int i = blockIdx.x * 256 + threadIdx.x;
  int r = i >> 8, c = i & 255;
  if (r < rows) out[i] = embW[(size_t)tok[r]*Ee + c];
}

// f32 -> bf16 row-major
__global__ void k_extract_bf16(const float* __restrict__ src, unsigned short* __restrict__ dst,
                               int n){
  int i = blockIdx.x * 256 + threadIdx.x;
  if (i < n) dst[i] = f2bf(src[i]);
}

// f32 [rows][256] -> chunked bf16 [32][rows][8]  (kb-major for coalesced staging)
__global__ void k_chunkw(const float* __restrict__ src, unsigned short* __restrict__ dst, int rows){
  int idx = blockIdx.x * 256 + threadIdx.x;
  if (idx < rows * 256){
    int i = idx & 7, r = (idx >> 3) % rows, kb = idx / (rows * 8);
    dst[idx] = f2bf(src[(size_t)r*256 + kb*8 + i]);
  }
}

// projf f32 [B*TE][768] -> chunked bf16 [B][16][768][8]
__global__ void k_projchunk(const float* __restrict__ in, unsigned short* __restrict__ out){
  int idx = blockIdx.x * 256 + threadIdx.x;     // total B*16*768*8
  int i = idx & 7;
  int t1 = idx >> 3;
  int n = t1 % 768;
  int t2 = t1 / 768;
  int kb = t2 & 15, b = t2 >> 4;
  out[idx] = f2bf(in[(size_t)(b*TEe + kb*8 + i)*768 + n]);
}

// ---------------- bf16 MFMA GEMM: C[M,N] = A[M,K] * B^T + bias ----------------
template<bool A_BF16, bool B_BF16, bool B_KMAJOR, bool OUT_BF16>
__global__ __launch_bounds__(256) void k_gemm(
  const void* __restrict__ Av, const void* __restrict__ Bv,
  const float* __restrict__ bias, void* __restrict__ Cv,
  int M, int N, int K, int lda, int ldb, int ldc)
{
  __shared__ unsigned short lA[128*40];
  __shared__ unsigned short lB[128*40];
  const int tid  = threadIdx.x;
  const int lane = tid & 63;
  const int w = tid >> 6, wr = w >> 1, wc = w & 1;
  const int m0 = blockIdx.y * 128, n0 = blockIdx.x * 128;
  f32x4 acc[4][4];
  #pragma unroll
  for (int i = 0; i < 4; ++i)
    #pragma unroll
    for (int j = 0; j < 4; ++j) acc[i][j] = (f32x4){0.f,0.f,0.f,0.f};

  for (int k0 = 0; k0 < K; k0 += 32){
    if (A_BF16){
      const unsigned short* A = (const unsigned short*)Av;
      #pragma unroll
      for (int it = 0; it < 2; ++it){
        int idx = tid + it*256; int r = idx >> 2, q = idx & 3;
        *(uint4v*)&lA[r*40 + q*8] = *(const uint4v*)(A + (size_t)(m0+r)*lda + k0 + q*8);
      }
    } else {
      const float* A = (const float*)Av;
      #pragma unroll
      for (int it = 0; it < 4; ++it){
        int idx = tid + it*256; int r = idx >> 3, q = idx & 7;
        f32x4 v = *(const f32x4*)(A + (size_t)(m0+r)*lda + k0 + q*4);
        uint2v pk; pk[0] = pack2(v[0], v[1]); pk[1] = pack2(v[2], v[3]);
        *(uint2v*)&lA[r*40 + q*4] = pk;
      }
    }
    if (B_KMAJOR){
      const float* Bp = (const float*)Bv;
      #pragma unroll
      for (int it = 0; it < 4; ++it){
        int idx = tid + it*256; int kk = idx >> 5, nq = idx & 31;
        f32x4 v = *(const f32x4*)(Bp + (size_t)(k0+kk)*ldb + n0 + nq*4);
        #pragma unroll
        for (int s2 = 0; s2 < 4; ++s2) lB[(nq*4+s2)*40 + kk] = f2bf(v[s2]);
      }
    } else if (B_BF16){
      const unsigned short* Bp = (const unsigned short*)Bv;
      #pragma unroll
      for (int it = 0; it < 2; ++it){
        int idx = tid + it*256; int r = idx >> 2, q = idx & 3;
        *(uint4v*)&lB[r*40 + q*8] = *(const uint4v*)(Bp + (size_t)(n0+r)*ldb + k0 + q*8);
      }
    } else {
      const float* Bp = (const float*)Bv;
      #pragma unroll
      for (int it = 0; it < 4; ++it){
        int idx = tid + it*256; int r = idx >> 3, q = idx & 7;
        f32x4 v = *(const f32x4*)(Bp + (size_t)(n0+r)*ldb + k0 + q*4);
        uint2v pk; pk[0] = pack2(v[0], v[1]); pk[1] = pack2(v[2], v[3]);
        *(uint2v*)&lB[r*40 + q*4] = pk;
      }
    }
    __syncthreads();
    short8 av[4], bv[4];
    #pragma unroll
    for (int i = 0; i < 4; ++i)
      av[i] = *(const short8*)&lA[(wr*64 + i*16 + (lane&15))*40 + (lane>>4)*8];
    #pragma unroll
    for (int j = 0; j < 4; ++j)
      bv[j] = *(const short8*)&lB[(wc*64 + j*16 + (lane&15))*40 + (lane>>4)*8];
    #pragma unroll
    for (int i = 0; i < 4; ++i)
      #pragma unroll
      for (int j = 0; j < 4; ++j)
        acc[i][j] = __builtin_amdgcn_mfma_f32_16x16x32_bf16(av[i], bv[j], acc[i][j], 0, 0, 0);
    __syncthreads();
  }
  #pragma unroll
  for (int i = 0; i < 4; ++i){
    #pragma unroll
    for (int j = 0; j < 4; ++j){
      int col = n0 + wc*64 + j*16 + (lane & 15);
      float bb = bias ? bias[col] : 0.f;
      #pragma unroll
      for (int r = 0; r < 4; ++r){
        int row = m0 + wr*64 + i*16 + (lane>>4)*4 + r;
        float v = acc[i][j][r] + bb;
        if (OUT_BF16) ((unsigned short*)Cv)[(size_t)row*ldc + col] = f2bf(v);
        else          ((float*)Cv)[(size_t)row*ldc + col] = v;
      }
    }
  }
}

// ---------------- encoder: 64 blocks = (dir, batch), 1024 threads ----------------
// R11 version (measured best ~534us): rows 0-255 in LDS (quarter-split, low
// conflict); rows 256-767 streamed as half-rows with a DEPTH-8 register ring.
// (R12's 512-thr port regressed: 2-thr/row LDS split hit 8-way bank conflicts
// and halved wave-level latency hiding.)
__global__ __launch_bounds__(1024) void k_encoder(
  const unsigned short* __restrict__ Whf, const unsigned short* __restrict__ Whb,
  const float* __restrict__ bhf, const float* __restrict__ bhb,
  const float* __restrict__ gif, const float* __restrict__ gib,
  float* __restrict__ encoded)
{
  extern __shared__ char smem[];
  unsigned short* lw = (unsigned short*)smem;        // 131072
  float* hA   = (float*)(smem + 131072);             // 1024
  float* hB   = (float*)(smem + 132096);             // 1024
  float* parA = (float*)(smem + 133120);             // 4096
  float* parB = (float*)(smem + 137216);             // 4096
  const int dir = blockIdx.x & 1, b = blockIdx.x >> 1;
  const unsigned short* Wh = dir ? Whb : Whf;
  const float* bh = dir ? bhb : bhf;
  const float* gi = dir ? gib : gif;
  const int T = threadIdx.x;
  const int rl = T & 255, q4 = T >> 8;
  const int rrh = T & 511, hf = T >> 9;
  const unsigned short* wsrc = Wh + (size_t)(hf*16)*6144 + (size_t)(256 + rrh)*8;
  uint4v wb[8];
  #pragma unroll
  for (int d = 0; d < 8; ++d) wb[d] = *(const uint4v*)(wsrc + (size_t)d*6144);
  for (int cc = T; cc < 256*32; cc += 1024){
    int r = cc >> 5, q = cc & 31;
    *(uint4v*)&lw[(r*32 + (q ^ (r & 31)))*8] = *(const uint4v*)(Wh + (size_t)q*6144 + r*8);
  }
  float bh0 = 0.f, bh1 = 0.f, bh2 = 0.f;
  if (T < 256){ bh0 = bh[T]; bh1 = bh[T+256]; bh2 = bh[T+512]; hA[T] = 0.f; }
  __syncthreads();
  const float* hc = hA; float* hn = hB;
  for (int s = 0; s < TEe; ++s){
    const int t = dir ? (TEe-1-s) : s;
    // LDS-part: quarter q4 of row rl
    float aL = 0.f;
    #pragma unroll
    for (int i = 0; i < 8; ++i){
      const int ck = q4*8 + i;
      float hr[8];
      *(f32x4*)&hr[0] = *(const f32x4*)&hc[ck*8];
      *(f32x4*)&hr[4] = *(const f32x4*)&hc[ck*8+4];
      aL += dot8(*(const uint4v*)&lw[(rl*32 + (ck ^ (rl & 31)))*8], hr);
    }
    parA[q4*256 + rl] = aL;
    // stream-part: half hf of row 256+rrh, depth-8 ring
    float aR = 0.f;
    const float* hh = hc + hf*128;
    #pragma unroll
    for (int q = 0; q < 16; ++q){
      float hr[8];
      *(f32x4*)&hr[0] = *(const f32x4*)&hh[q*8];
      *(f32x4*)&hr[4] = *(const f32x4*)&hh[q*8+4];
      aR += dot8(wb[q & 7], hr);
      wb[q & 7] = *(const uint4v*)(wsrc + (size_t)((q < 8) ? (q + 8) : (q - 8))*6144);
    }
    parB[hf*512 + rrh] = aR;
    __syncthreads();                   // B1: partials ready
    if (T < 256){
      const int j = T;
      const float* grow = gi + (size_t)(b*TEe + t)*768;
      const float A0 = parA[j] + parA[256+j] + parA[512+j] + parA[768+j] + bh0;
      const float A1 = parB[j] + parB[512+j] + bh1;
      const float A2 = parB[256+j] + parB[768+j] + bh2;
      const float r = sigmoidf_(grow[j] + A0);
      const float z = sigmoidf_(grow[j+256] + A1);
      const float n = tanhf(grow[j+512] + r*A2);
      const float hnew = (1.f - z)*n + z*hc[j];
      hn[j] = hnew;
      encoded[(size_t)(b*TEe + t)*512 + dir*256 + j] = hnew;
    }
    __syncthreads();                   // B2: h_new visible
    const float* tmp = hc; hc = hn; hn = (float*)tmp;
  }
}

// encb2[r] = encoded[r,:512] . W2_b
__global__ void k_encb2(const float* __restrict__ encoded, const float* __restrict__ W2b,
                        float* __restrict__ encb2){
  int r = blockIdx.x, l = threadIdx.x;
  const float* e = encoded + (size_t)r*512;
  float s = 0.f;
  for (int k = l; k < 512; k += 64) s += e[k]*W2b[k];
  for (int off = 32; off; off >>= 1) s += __shfl_down(s, off);
  if (l == 0) encb2[r] = s;
}

__global__ void k_hinit(const float* __restrict__ encoded, const int* __restrict__ sizes,
                        const float* __restrict__ W1w, const float* __restrict__ W1b,
                        float* __restrict__ h0){
  int b = blockIdx.x, o = threadIdx.x;
  int idx = sizes[b] - 1;
  idx = idx < 0 ? 0 : (idx > TEe-1 ? TEe-1 : idx);
  const float* ls = encoded + (size_t)(b*TEe + idx)*512;
  const float* wv = W1w + (size_t)o*512;
  float s = W1b[o];
  for (int k = 0; k < 512; k += 4){
    f32x4 a = *(const f32x4*)(ls + k);
    f32x4 w4 = *(const f32x4*)(wv + k);
    s = fmaf(a[0],w4[0], fmaf(a[1],w4[1], fmaf(a[2],w4[2], fmaf(a[3],w4[3], s))));
  }
  h0[b*256 + o] = s;
}

// ---------------- decoder: 32 blocks = batch, 512 threads ----------------
// R12 version (measured ~316us): 512 threads -> 128-VGPR cap -> depth-8/4/2
// register rings persist (VGPR_Count=128 confirmed). 4 barriers/step.
// n-gate: ctx (gc) stays OUTSIDE the r* product; bh_n INSIDE (ref semantics).
#define DLR 128
__global__ __launch_bounds__(512, 1) void k_decoder(
  const unsigned short* __restrict__ Whd, const float* __restrict__ bhd,
  const float* __restrict__ gidx,            // [B][TD][768] f32 (includes bi_d)
  const unsigned short* __restrict__ encw2,  // [B*TE][256] bf16
  const float* __restrict__ encb2,           // [B*TE]
  const unsigned short* __restrict__ projt,  // [B][16][768][8] bf16
  const float* __restrict__ h0,
  unsigned short* __restrict__ outs_bf)      // [B][TD][256] bf16
{
  extern __shared__ char smem[];
  unsigned short* le = (unsigned short*)smem;            // 65536
  unsigned short* lw = (unsigned short*)(smem + 65536);  // DLR*512 = 65536
  float* h    = (float*)(smem + 131072);                 // 1024
  float* parL = (float*)(smem + 132096);                 // 2048 (4 quarters x 128)
  float* parS1= (float*)(smem + 134144);                 // 2048 (rows 128-639)
  float* parS2= (float*)(smem + 136192);                 // 2048 (4 quarters x 128, rows 640-767)
  float* gcs  = (float*)(smem + 138240);                 // 2048 (ctx rows 0-511)
  float* cpar = (float*)(smem + 140288);                 // 2048 (2 halves x 256, ctx rows 512-767)
  float* p    = (float*)(smem + 142336);                 // 512
  float* ebl  = (float*)(smem + 142848);                 // 512 -> total 143360
  const int b = blockIdx.x, T = threadIdx.x;             // [0,512)
  const unsigned short* ptc = projt + (size_t)b*98304;
  const unsigned short* wsrcM = Whd + (size_t)(DLR + T)*8;     // rows 128..639
  const int trow = 640 + (T >> 2), tq = (T & 3)*8;             // rows 640..767
  const unsigned short* wsrcT = Whd + (size_t)trow*8;
  const unsigned short* csrcM = ptc + (size_t)T*8;             // ctx rows 0..511
  const int crow = 512 + (T >> 1), cq = (T & 1)*8;             // ctx rows 512..767
  const unsigned short* csrcT = ptc + (size_t)crow*8;
  uint4v wb[8], wb2[2], cb[4], cb2[2];
  #pragma unroll
  for (int d = 0; d < 8; ++d) wb[d] = *(const uint4v*)(wsrcM + (size_t)d*6144);
  wb2[0] = *(const uint4v*)(wsrcT + (size_t)tq*6144);
  wb2[1] = *(const uint4v*)(wsrcT + (size_t)(tq+1)*6144);
  #pragma unroll
  for (int d = 0; d < 4; ++d) cb[d] = *(const uint4v*)(csrcM + (size_t)d*6144);
  cb2[0] = *(const uint4v*)(csrcT + (size_t)cq*6144);
  cb2[1] = *(const uint4v*)(csrcT + (size_t)(cq+1)*6144);
  for (int cc = T; cc < 128*32; cc += 512){
    int r = cc >> 5, q = cc & 31;
    *(uint4v*)&le[(r*32 + (q ^ (r & 31)))*8] =
        *(const uint4v*)(encw2 + ((size_t)(b*TEe + r) << 8) + (q << 3));
  }
  for (int cc = T; cc < DLR*32; cc += 512){
    int r = cc >> 5, q = cc & 31;
    *(uint4v*)&lw[(r*32 + (q ^ (r & 31)))*8] =
        *(const uint4v*)(Whd + (size_t)q*6144 + r*8);
  }
  for (int i = T; i < 256; i += 512) h[i] = h0[b*256 + i];
  gcs[T] = 0.f; cpar[T] = 0.f;                           // ctx_init = 0
  if (T < TEe) ebl[T] = encb2[b*TEe + T];
  float bh0 = 0.f, bh1 = 0.f, bh2 = 0.f;
  if (T < 256){ bh0 = bhd[T]; bh1 = bhd[T+256]; bh2 = bhd[T+512]; }
  __syncthreads();
  float g0 = 0.f, g1 = 0.f, g2 = 0.f;
  if (T < 256){
    const float* grow = gidx + (size_t)(b*TDd)*768;
    g0 = grow[T]; g1 = grow[T+256]; g2 = grow[T+512];
  }
  #define DOTS_BODY                                                            \
  {                                                                            \
    { const int rL2 = T >> 2, qb = (T & 3)*8;                                  \
      const unsigned short* lwr = lw + rL2*256;                                \
      float a = 0.f;                                                           \
      _Pragma("unroll")                                                        \
      for (int i = 0; i < 8; ++i){                                             \
        const int q = qb + i;                                                  \
        float hr[8];                                                           \
        *(f32x4*)&hr[0] = *(const f32x4*)&h[q*8];                              \
        *(f32x4*)&hr[4] = *(const f32x4*)&h[q*8+4];                            \
        a += dot8(*(const uint4v*)(lwr + ((q ^ (rL2 & 31)) << 3)), hr);        \
      }                                                                        \
      parL[(T & 3)*128 + rL2] = a;                                             \
    }                                                                          \
    { float a = 0.f;                                                           \
      _Pragma("unroll")                                                        \
      for (int q = 0; q < 32; ++q){                                            \
        float hr[8];                                                           \
        *(f32x4*)&hr[0] = *(const f32x4*)&h[q*8];                              \
        *(f32x4*)&hr[4] = *(const f32x4*)&h[q*8+4];                            \
        a += dot8(wb[q & 7], hr);                                              \
        wb[q & 7] = *(const uint4v*)(wsrcM + (size_t)((q < 24) ? (q + 8) : (q - 24))*6144); \
      }                                                                        \
      parS1[T] = a;                                                            \
    }                                                                          \
    { float a = 0.f;                                                           \
      _Pragma("unroll")                                                        \
      for (int i = 0; i < 8; ++i){                                             \
        const int q = tq + i;                                                  \
        float hr[8];                                                           \
        *(f32x4*)&hr[0] = *(const f32x4*)&h[q*8];                              \
        *(f32x4*)&hr[4] = *(const f32x4*)&h[q*8+4];                            \
        a += dot8(wb2[i & 1], hr);                                             \
        wb2[i & 1] = *(const uint4v*)(wsrcT + (size_t)(tq + ((i < 6) ? (i + 2) : (i - 6)))*6144); \
      }                                                                        \
      parS2[(T & 3)*128 + (T >> 2)] = a;                                       \
    }                                                                          \
  }
  DOTS_BODY
  __syncthreads();
  for (int t = 0; t < TDd; ++t){
    if (T < 256){
      const int j = T;
      float A0, A2;
      if (j < 128){
        A0 = parL[j] + parL[128+j] + parL[256+j] + parL[384+j];
        A2 = parS1[384+j];
      } else {
        A0 = parS1[j-128];
        A2 = parS2[j-128] + parS2[j] + parS2[j+128] + parS2[j+256];
      }
      const float A1 = parS1[128+j];
      const float gcr = gcs[j];
      const float gcz = gcs[256+j];
      const float gcn = cpar[j] + cpar[256+j];
      const float r = sigmoidf_(g0 + gcr + A0 + bh0);
      const float z = sigmoidf_(g1 + gcz + A1 + bh1);
      const float n = tanhf(g2 + gcn + r*(A2 + bh2));
      const float hnew = (1.f - z)*n + z*h[j];
      h[j] = hnew;
      outs_bf[(size_t)(b*TDd + t)*256 + j] = f2bf(hnew);
    }
    if (t + 1 == TDd) break;
    __syncthreads();                   // B1: h_t visible
    if (T < 256){
      const float* grow = gidx + (size_t)(b*TDd + t + 1)*768;
      g0 = grow[T]; g1 = grow[T+256]; g2 = grow[T+512];
    }
    DOTS_BODY
    {
      const int pos = T >> 2, kq = (T & 3)*8;
      const unsigned short* er = le + pos*256;
      float s = 0.f;
      #pragma unroll
      for (int i = 0; i < 8; ++i){
        const int q = kq + i;
        float hr[8];
        *(f32x4*)&hr[0] = *(const f32x4*)&h[q*8];
        *(f32x4*)&hr[4] = *(const f32x4*)&h[q*8+4];
        s += dot8(*(const uint4v*)(er + ((q ^ (pos & 31)) << 3)), hr);
      }
      s += __shfl_xor(s, 1);
      s += __shfl_xor(s, 2);
      if ((T & 3) == 0) p[pos] = s + ebl[pos];
    }
    __syncthreads();                   // B2: raw scores ready
    if (T < 64){
      float m = fmaxf(p[T], p[T+64]);
      for (int off = 32; off; off >>= 1) m = fmaxf(m, __shfl_xor(m, off));
      float e0 = __expf(p[T] - m), e1 = __expf(p[T+64] - m);
      float ss = e0 + e1;
      for (int off = 32; off; off >>= 1) ss += __shfl_xor(ss, off);
      float inv = 1.f / ss;
      p[T] = e0*inv; p[T+64] = e1*inv;
    }
    __syncthreads();                   // B3: softmax done
    {
      float c = 0.f;
      #pragma unroll
      for (int q = 0; q < 16; ++q){
        float pr[8];
        *(f32x4*)&pr[0] = *(const f32x4*)&p[q*8];
        *(f32x4*)&pr[4] = *(const f32x4*)&p[q*8+4];
        c += dot8(cb[q & 3], pr);
        cb[q & 3] = *(const uint4v*)(csrcM + (size_t)((q < 12) ? (q + 4) : (q - 12))*6144);
      }
      gcs[T] = c;
      float c2 = 0.f;
      #pragma unroll
      for (int i = 0; i < 8; ++i){
        const int q = cq + i;
        float pr[8];
        *(f32x4*)&pr[0] = *(const f32x4*)&p[q*8];
        *(f32x4*)&pr[4] = *(const f32x4*)&p[q*8+4];
        c2 += dot8(cb2[i & 1], pr);
        cb2[i & 1] = *(const uint4v*)(csrcT + (size_t)(cq + ((i < 6) ? (i + 2) : (i - 6)))*6144);
      }
      cpar[(T & 1)*256 + (T >> 1)] = c2;
    }
    __syncthreads();                   // B4: gcs/cpar ready for next gates
  }
  #undef DOTS_BODY
}

extern "C" void kernel_launch(void* const* d_in, const int* in_sizes, int n_in,
                              void* d_out, int out_size, void* d_ws, size_t ws_size,
                              hipStream_t stream)
{
  (void)in_sizes; (void)n_in; (void)out_size;
  const int*   enc_in = (const int*)d_in[0];
  const int*   dec_in = (const int*)d_in[1];
  const float* embW   = (const float*)d_in[2];
  const float* Wi_f   = (const float*)d_in[3];
  const float* Wh_f   = (const float*)d_in[4];
  const float* bi_f   = (const float*)d_in[5];
  const float* bh_f   = (const float*)d_in[6];
  const float* Wi_b   = (const float*)d_in[7];
  const float* Wh_b   = (const float*)d_in[8];
  const float* bi_b   = (const float*)d_in[9];
  const float* bh_b   = (const float*)d_in[10];
  const float* Wi_d   = (const float*)d_in[11];
  const float* Wh_d   = (const float*)d_in[12];
  const float* bi_d   = (const float*)d_in[13];
  const float* bh_d   = (const float*)d_in[14];
  const float* W1_w   = (const float*)d_in[15];
  const float* W1_b   = (const float*)d_in[16];
  const float* W2_w   = (const float*)d_in[17];
  const float* W2_b   = (const float*)d_in[18];
  const float* lin_w  = (const float*)d_in[19];
  const float* lin_b  = (const float*)d_in[20];

  char* scr = (char*)d_out;
  float* emb_enc = (float*)(scr + 0);
  float* emb_dec = (float*)(scr + 4194304);
  float* gi_f    = (float*)(scr + 6291456);
  float* gi_b    = (float*)(scr + 18874368);
  float* gi_dx   = (float*)(scr + 31457280);
  float* enc     = (float*)(scr + 37748736);
  float* projf   = (float*)(scr + 46137344);
  unsigned short* whf_bf = (unsigned short*)(scr + 58720256);
  unsigned short* whb_bf = (unsigned short*)(scr + 59113472);
  unsigned short* whd_bf = (unsigned short*)(scr + 59506688);
  unsigned short* encw2  = (unsigned short*)(scr + 59899904);
  unsigned short* projt  = (unsigned short*)(scr + 61997056);
  float* encb2 = (float*)(scr + 68288512);
  int*   sizes = (int*)(scr + 68304896);
  float* h0    = (float*)(scr + 68305024);

  unsigned short* outs_bf = (unsigned short*)d_ws;
  unsigned short* lin_bf  = (unsigned short*)((char*)d_ws + (1<<20));
  const bool big = ws_size >= (size_t)(1<<20) + 16384000u + 1024u;

  // allow >64KB dynamic LDS (capture-safe host attribute; idempotent)
  hipFuncSetAttribute((const void*)k_encoder, hipFuncAttributeMaxDynamicSharedMemorySize, 141312);
  hipFuncSetAttribute((const void*)k_decoder, hipFuncAttributeMaxDynamicSharedMemorySize, 143360);

  k_sizes<<<1, 32, 0, stream>>>(enc_in, sizes);
  k_gather<<<Bb*TEe, 256, 0, stream>>>(enc_in, embW, emb_enc, Bb*TEe);
  k_gather<<<Bb*TDd, 256, 0, stream>>>(dec_in, embW, emb_dec, Bb*TDd);
  k_chunkw<<<768, 256, 0, stream>>>(Wh_f, whf_bf, 768);
  k_chunkw<<<768, 256, 0, stream>>>(Wh_b, whb_bf, 768);
  k_chunkw<<<768, 256, 0, stream>>>(Wh_d, whd_bf, 768);
  if (big) k_extract_bf16<<<32000, 256, 0, stream>>>(lin_w, lin_bf, 32000*256);

  k_gemm<false,false,false,false><<<dim3(6,32), 256, 0, stream>>>(
      emb_enc, Wi_f, bi_f, gi_f, 4096, 768, 256, 256, 256, 768);
  k_gemm<false,false,false,false><<<dim3(6,32), 256, 0, stream>>>(
      emb_enc, Wi_b, bi_b, gi_b, 4096, 768, 256, 256, 256, 768);
  k_gemm<false,false,false,false><<<dim3(6,16), 256, 0, stream>>>(
      emb_dec, Wi_d + 512, bi_d, gi_dx, 2048, 768, 256, 256, 768, 768);

  k_encoder<<<64, 1024, 141312, stream>>>(whf_bf, whb_bf, bh_f, bh_b, gi_f, gi_b, enc);
  k_encb2<<<Bb*TEe, 64, 0, stream>>>(enc, W2_b, encb2);

  k_gemm<false,false,true,true><<<dim3(2,32), 256, 0, stream>>>(
      enc, W2_w, nullptr, encw2, 4096, 256, 512, 512, 256, 256);
  k_gemm<false,false,false,false><<<dim3(6,32), 256, 0, stream>>>(
      enc, Wi_d, nullptr, projf, 4096, 768, 512, 512, 768, 768);
  k_projchunk<<<(Bb*16*768*8)/256, 256, 0, stream>>>(projf, projt);
  k_hinit<<<Bb, 256, 0, stream>>>(enc, sizes, W1_w, W1_b, h0);

  k_decoder<<<Bb, 512, 143360, stream>>>(whd_bf, bh_d, gi_dx, encw2, encb2, projt, h0, outs_bf);

  if (big)
    k_gemm<true,true,false,false><<<dim3(250,16), 256, 0, stream>>>(
        outs_bf, lin_bf, lin_b, d_out, 2048, 32000, 256, 256, 256, 32000);
  else
    k_gemm<true,false,false,false><<<dim3(250,16), 256, 0, stream>>>(
        outs_bf, lin_w, lin_b, d_out, 2048, 32000, 256, 256, 256, 32000);
}